// Round 9
// baseline (2291.042 us; speedup 1.0000x reference)
//
#include <hip/hip_runtime.h>
#include <hip/hip_bf16.h>
#include <math.h>

typedef unsigned short u16;
typedef __attribute__((ext_vector_type(8))) short bf16x8;
typedef __attribute__((ext_vector_type(8))) unsigned short u16x8;
typedef __attribute__((ext_vector_type(4))) float f32x4;

#define MFMA_BF16 __builtin_amdgcn_mfma_f32_16x16x32_bf16

__device__ __forceinline__ u16 f2bf(float f){
  union { float f; unsigned u; } v; v.f = f;
  unsigned r = v.u + 0x7FFFu + ((v.u >> 16) & 1u);
  return (u16)(r >> 16);
}

__device__ __forceinline__ void gll16(const void* g, void* l){
  __builtin_amdgcn_global_load_lds(
      (const __attribute__((address_space(1))) unsigned int*)g,
      (__attribute__((address_space(3))) unsigned int*)l, 16, 0, 0);
}

__global__ void k_concat_bias(const float* __restrict__ a, const float* __restrict__ b,
                              const float* __restrict__ c, float* __restrict__ o){
  int i = threadIdx.x;  // 768 threads
  o[i] = i < 256 ? a[i] : (i < 512 ? b[i-256] : c[i-512]);
}

// ---- weights -> MFMA-fragment-major: F[n16][ks][lane][8] = W[k][n],
// k = ks*32 + (lane>>4)*8 + j, n = n16*16 + (lane&15)
__global__ __launch_bounds__(256) void k_wfrag(const float* __restrict__ W, u16* __restrict__ F,
                                               int K, int N){
  int idx = blockIdx.x*256 + threadIdx.x;
  int nks = K >> 5;
  int per_n16 = nks << 9;
  int n16 = idx / per_n16; int rem = idx - n16*per_n16;
  int ks = rem >> 9, l8 = rem & 511, lane = l8 >> 3, j = l8 & 7;
  int k = ks*32 + ((lane >> 4) << 3) + j;
  int n = (n16 << 4) + (lane & 15);
  F[idx] = f2bf(W[(size_t)k*N + n]);
}

// ---- QKV weights fragment-major (per head) ----
__global__ __launch_bounds__(256) void k_fragw(const float* __restrict__ wq, const float* __restrict__ wk,
                                               const float* __restrict__ wv, u16* __restrict__ fragW){
  int idx = blockIdx.x*256 + threadIdx.x;    // 3*65536
  int j = idx & 7, lane = (idx >> 3) & 63, nj = (idx >> 9) & 1;
  int ks = (idx >> 10) & 7, h = (idx >> 13) & 7, type = idx >> 16;
  const float* w = type == 0 ? wq : (type == 1 ? wk : wv);
  int k = ks*32 + 8*(lane >> 4) + j;
  int n = h*32 + nj*16 + (lane & 15);
  fragW[idx] = f2bf(w[(size_t)k*256 + n]);
}

// ---- fused rel-pos bias + shift mask, fragment layout: fb2[cls][h][m][lr][nj] ----
__global__ __launch_bounds__(256) void k_bias(const float* __restrict__ btab, float* __restrict__ fb){
  int idx = blockIdx.x*256 + threadIdx.x;   // 4*8*64*64 = 131072
  int nj = idx & 3, lr = (idx >> 2) & 15, m = (idx >> 6) & 63, hh = (idx >> 12) & 7, cls = idx >> 15;
  int n = nj*16 + lr;
  int r1=m>>3, c1=m&7, r2=n>>3, c2=n&7;
  float bv = btab[((r1-r2+7)*15 + (c1-c2+7))*8 + hh];
  int whe = cls>>1, wwe = cls&1;
  int a1 = (whe ? (r1<4?1:2) : 0)*3 + (wwe ? (c1<4?1:2) : 0);
  int a2 = (whe ? (r2<4?1:2) : 0)*3 + (wwe ? (c2<4?1:2) : 0);
  fb[idx] = bv + ((a1!=a2) ? -100.f : 0.f);
}

// ======== FUSED LN1 + QKV-projection + windowed attention ========
__global__ __launch_bounds__(512) void k_fattn(const float* __restrict__ hidden,
    const float* __restrict__ g1, const float* __restrict__ b1f,
    const u16* __restrict__ fragW, const float* __restrict__ bqkv,
    const float* __restrict__ fb, u16* __restrict__ outp)
{
  __shared__ __align__(16) u16 lds[75840];   // 151680 B
  int tid = threadIdx.x, lane = tid & 63, wid = tid >> 6;
  int lg = lane >> 4, lr = lane & 15;
  int gw = blockIdx.x;
  int bi = gw >> 6, win = gw & 63, wh = win >> 3, wwi = win & 7;

  // ---- Phase 1: LN1 + cyclic-shift gather -> xb (chunk-XOR swizzled) ----
  {
    int t = wid*8 + (lane >> 3);
    int j = lane & 7;
    int hh_ = (wh*8 + (t >> 3) + 4) & 63;
    int ww_ = (wwi*8 + (t & 7) + 4) & 63;
    const float4* row = (const float4*)(hidden + ((size_t)bi*4096 + hh_*64 + ww_)*256) + j*8;
    float4 v[8]; float s = 0.f, sq = 0.f;
#pragma unroll
    for (int i=0;i<8;i++){
      v[i] = row[i];
      s  += v[i].x+v[i].y+v[i].z+v[i].w;
      sq += v[i].x*v[i].x+v[i].y*v[i].y+v[i].z*v[i].z+v[i].w*v[i].w;
    }
    s += __shfl_xor(s,1); sq += __shfl_xor(sq,1);
    s += __shfl_xor(s,2); sq += __shfl_xor(sq,2);
    s += __shfl_xor(s,4); sq += __shfl_xor(sq,4);
    float mean = s*(1.f/256.f);
    float inv = rsqrtf(sq*(1.f/256.f) - mean*mean + 1e-5f);
    const float4* gg = (const float4*)g1 + j*8;
    const float4* bb = (const float4*)b1f + j*8;
#pragma unroll
    for (int i2=0;i2<4;i2++){
      float4 a0=v[2*i2], a1=v[2*i2+1];
      float4 g0=gg[2*i2], g1_=gg[2*i2+1];
      float4 b0=bb[2*i2], b1_=bb[2*i2+1];
      u16x8 pk;
      pk[0]=f2bf((a0.x-mean)*inv*g0.x+b0.x); pk[1]=f2bf((a0.y-mean)*inv*g0.y+b0.y);
      pk[2]=f2bf((a0.z-mean)*inv*g0.z+b0.z); pk[3]=f2bf((a0.w-mean)*inv*g0.w+b0.w);
      pk[4]=f2bf((a1.x-mean)*inv*g1_.x+b1_.x); pk[5]=f2bf((a1.y-mean)*inv*g1_.y+b1_.y);
      pk[6]=f2bf((a1.z-mean)*inv*g1_.z+b1_.z); pk[7]=f2bf((a1.w-mean)*inv*g1_.w+b1_.w);
      int c = (j*4+i2) ^ (t & 7);
      *(u16x8*)(&lds[t*256 + c*8]) = pk;
    }
  }
  __syncthreads();

  // ---- Phase 2: mini-GEMM q/k/v for head `wid` (coalesced fragW from L2) ----
  f32x4 qa[4][2]={}, ka[4][2]={}, va[4][2]={};
  __builtin_amdgcn_s_setprio(1);
#pragma unroll
  for (int ks=0; ks<8; ks++){
    bf16x8 af[4];
#pragma unroll
    for (int mi=0;mi<4;mi++){
      int tok = mi*16+lr;
      af[mi] = *(const bf16x8*)(&lds[tok*256 + (((ks*4+lg) ^ (tok&7))*8)]);
    }
    const u16* fq = fragW + ((((size_t)wid)*8 + ks)*2)*512 + lane*8;
#pragma unroll
    for (int nj=0;nj<2;nj++){
      bf16x8 bq_ = *(const bf16x8*)(fq + nj*512);
      bf16x8 bk_ = *(const bf16x8*)(fq + 65536 + nj*512);
      bf16x8 bv_ = *(const bf16x8*)(fq + 131072 + nj*512);
#pragma unroll
      for (int mi=0;mi<4;mi++){
        qa[mi][nj] = MFMA_BF16(af[mi], bq_, qa[mi][nj], 0,0,0);
        ka[mi][nj] = MFMA_BF16(af[mi], bk_, ka[mi][nj], 0,0,0);
        va[mi][nj] = MFMA_BF16(af[mi], bv_, va[mi][nj], 0,0,0);
      }
    }
  }
  __builtin_amdgcn_s_setprio(0);

  // ---- Phase 3: q/k/v -> wave-private LDS ----
  u16* q_l = &lds[16384 + wid*7432];
  u16* k_l = q_l + 2560;
  u16* v_l = q_l + 5120;
  const float scale = 0.1767766952966369f; // 32^-0.5
#pragma unroll
  for (int mi=0;mi<4;mi++)
#pragma unroll
  for (int nj=0;nj<2;nj++){
    int dim = nj*16+lr;
    float bq_ = bqkv[wid*32+dim], bk_ = bqkv[256+wid*32+dim], bv_ = bqkv[512+wid*32+dim];
#pragma unroll
    for (int r=0;r<4;r++){
      int tok = mi*16+4*lg+r;
      q_l[tok*40+dim] = f2bf((qa[mi][nj][r]+bq_)*scale);
      k_l[tok*40+dim] = f2bf(ka[mi][nj][r]+bk_);
    }
    ushort4 vp;
    vp.x = f2bf(va[mi][nj][0]+bv_); vp.y = f2bf(va[mi][nj][1]+bv_);
    vp.z = f2bf(va[mi][nj][2]+bv_); vp.w = f2bf(va[mi][nj][3]+bv_);
    *(ushort4*)(&v_l[dim*72 + mi*16 + 4*lg]) = vp;
  }

  // ---- Phase 4: QK^T + bias/mask + softmax ----
  bf16x8 qf[4], kf[4];
#pragma unroll
  for (int i=0;i<4;i++){
    qf[i] = *(const bf16x8*)(&q_l[(i*16+lr)*40 + 8*lg]);
    kf[i] = *(const bf16x8*)(&k_l[(i*16+lr)*40 + 8*lg]);
  }
  f32x4 acc[4][4] = {};
#pragma unroll
  for (int mi=0;mi<4;mi++)
#pragma unroll
  for (int nj=0;nj<4;nj++)
    acc[mi][nj] = MFMA_BF16(qf[mi], kf[nj], acc[mi][nj], 0,0,0);

  int cls = ((wh==7) ? 2 : 0) | ((wwi==7) ? 1 : 0);
  const float4* fb4 = (const float4*)(fb + (((size_t)cls*8 + wid) << 12));
#pragma unroll
  for (int mi=0;mi<4;mi++)
#pragma unroll
  for (int r=0;r<4;r++){
    int m = mi*16 + 4*lg + r;
    float4 bv4 = fb4[m*16 + lr];
#pragma unroll
    for (int nj=0;nj<4;nj++)
      acc[mi][nj][r] += bv4[nj];
  }
#pragma unroll
  for (int mi=0;mi<4;mi++)
#pragma unroll
  for (int r=0;r<4;r++){
    float mx = fmaxf(fmaxf(acc[mi][0][r], acc[mi][1][r]), fmaxf(acc[mi][2][r], acc[mi][3][r]));
    for (int off=1; off<16; off<<=1) mx = fmaxf(mx, __shfl_xor(mx, off));
    float s = 0.f;
#pragma unroll
    for (int nj=0;nj<4;nj++){ float e = __expf(acc[mi][nj][r]-mx); acc[mi][nj][r]=e; s+=e; }
    for (int off=1; off<16; off<<=1) s += __shfl_xor(s, off);
    float inv = 1.f/s;
#pragma unroll
    for (int nj=0;nj<4;nj++) acc[mi][nj][r] *= inv;
  }

  // P overwrites q_l/k_l: fence (rule 18)
  asm volatile("s_waitcnt lgkmcnt(0)" ::: "memory");
  __builtin_amdgcn_sched_barrier(0);

  u16* P_l = q_l;   // [64][72]
#pragma unroll
  for (int mi=0;mi<4;mi++)
#pragma unroll
  for (int nj=0;nj<4;nj++)
#pragma unroll
  for (int r=0;r<4;r++)
    P_l[(mi*16+4*lg+r)*72 + nj*16 + lr] = f2bf(acc[mi][nj][r]);

  // ---- Phase 5: PV ----
  f32x4 acc2[4][2] = {};
#pragma unroll
  for (int ks=0; ks<2; ks++){
    bf16x8 vf0 = *(const bf16x8*)(&v_l[(lr)*72 + ks*32 + 8*lg]);
    bf16x8 vf1 = *(const bf16x8*)(&v_l[(16+lr)*72 + ks*32 + 8*lg]);
#pragma unroll
    for (int mi=0;mi<4;mi++){
      bf16x8 pf = *(const bf16x8*)(&P_l[(mi*16+lr)*72 + ks*32 + 8*lg]);
      acc2[mi][0] = MFMA_BF16(pf, vf0, acc2[mi][0], 0,0,0);
      acc2[mi][1] = MFMA_BF16(pf, vf1, acc2[mi][1], 0,0,0);
    }
  }

  // ---- Phase 6: out tile -> wave-private LDS [64][40-stride], vectorized store ----
  asm volatile("s_waitcnt lgkmcnt(0)" ::: "memory");
  __builtin_amdgcn_sched_barrier(0);
#pragma unroll
  for (int mi=0;mi<4;mi++)
#pragma unroll
  for (int nt=0;nt<2;nt++)
#pragma unroll
  for (int r=0;r<4;r++)
    q_l[(mi*16+4*lg+r)*40 + nt*16 + lr] = f2bf(acc2[mi][nt][r]);
  asm volatile("s_waitcnt lgkmcnt(0)" ::: "memory");
  __builtin_amdgcn_sched_barrier(0);
#pragma unroll
  for (int p=0;p<4;p++){
    int linear = p*512 + lane*8;
    int tok = linear >> 5, d = linear & 31;
    u16x8 val = *(const u16x8*)(&q_l[tok*40 + d]);
    *(u16x8*)(&outp[((size_t)gw*64 + tok)*256 + wid*32 + d]) = val;
  }
}

// ============ 256x256-tile GEMM: A[M][K] (LDS dbuf) @ Wfrag (L2-direct) ============
// 8 waves (2M x 4N), BK=64, A-only staging (64KB LDS -> 2 blocks/CU),
// counted vmcnt(4), B fragments prefetched into registers across barriers.
#define GSTAGE_A(buf, k0)                                                \
  _Pragma("unroll")                                                      \
  for (int c = 0; c < 4; c++){                                           \
    int row = c*64 + srow;                                               \
    gll16(Aw + (size_t)row*K + (k0) + (scb>>1), &As[buf][c*4096 + tid*8]); \
  }

#define BLOAD(t)                                                         \
  _Pragma("unroll")                                                      \
  for (int kk = 0; kk < 2; kk++){                                        \
    int ks = ((t)<<1) + kk;                                              \
    _Pragma("unroll")                                                    \
    for (int j = 0; j < 4; j++)                                          \
      bfr[kk][j] = *(const bf16x8*)(WF + ((((size_t)(nb16 + wc*4 + j))*nks + ks)<<9) + lane*8); \
  }

#define GLOOP_BODY(b)                                                    \
  _Pragma("unroll")                                                      \
  for (int kk = 0; kk < 2; kk++){                                        \
    int cbr = (kk*64 + 16*g) ^ ((lr & 7) << 4);                          \
    bf16x8 af[8];                                                        \
    _Pragma("unroll")                                                    \
    for (int i=0;i<8;i++)                                                \
      af[i] = *(const bf16x8*)(&As[b][(wr*128 + i*16 + lr)*64 + (cbr>>1)]); \
    _Pragma("unroll")                                                    \
    for (int mi=0;mi<8;mi++)                                             \
    _Pragma("unroll")                                                    \
    for (int nj=0;nj<4;nj++)                                             \
      acc[mi][nj] = MFMA_BF16(af[mi], bfr[kk][nj], acc[mi][nj], 0,0,0);  \
  }

#define GLOOP(nt)                                                        \
  GSTAGE_A(0, 0)                                                         \
  GSTAGE_A(1, 64)                                                        \
  BLOAD(0)                                                               \
  for (int t = 0; t < (nt); t++){                                        \
    if (t+1 < (nt)) asm volatile("s_waitcnt vmcnt(4)" ::: "memory");     \
    else            asm volatile("s_waitcnt vmcnt(0)" ::: "memory");     \
    __builtin_amdgcn_s_barrier();                                        \
    __builtin_amdgcn_sched_barrier(0);                                   \
    int b = t & 1;                                                       \
    GLOOP_BODY(b)                                                        \
    __builtin_amdgcn_sched_barrier(0);                                   \
    asm volatile("s_waitcnt lgkmcnt(0)" ::: "memory");                   \
    __builtin_amdgcn_s_barrier();                                        \
    __builtin_amdgcn_sched_barrier(0);                                   \
    if (t+1 < (nt)){ BLOAD(t+1) }                                        \
    if (t+2 < (nt)){ GSTAGE_A(b, (t+2)<<6) }                             \
  }

// EPI 2: +b1, exact GELU, bf16 row-major out [m][1024]
// EPI 3: +b2, +hs residual (fp32), fp32 out
template<int EPI, bool SWZ>
__global__ __launch_bounds__(512, 4) void k_gemm256(const u16* __restrict__ A, const u16* __restrict__ WF,
                                                    const float* __restrict__ bias, const float* __restrict__ res,
                                                    void* __restrict__ outp, int K){
  __shared__ __align__(16) u16 As[2][16384];
  int tid = threadIdx.x, lane = tid & 63, wid = tid >> 6;
  int g = lane >> 4, lr = lane & 15;
  int wr = wid >> 2, wc = wid & 3;
  int bx, by;
  if constexpr (SWZ){
    int nwg = gridDim.x*gridDim.y;
    int bid = blockIdx.y*gridDim.x + blockIdx.x;
    int cpx = nwg >> 3;
    int swz = (bid & 7)*cpx + (bid >> 3);
    bx = swz % gridDim.x; by = swz / gridDim.x;
  } else { bx = blockIdx.x; by = blockIdx.y; }
  int m0 = by*256, n0 = bx*256;
  int nb16 = bx << 4;
  int nks = K >> 5;
  const u16* Aw = A + (size_t)m0*K;
  int srow = tid >> 3;
  int scb  = ((tid & 7)*16) ^ ((srow & 7) << 4);
  f32x4 acc[8][4] = {};
  bf16x8 bfr[2][4];
  int nt = K >> 6;

  GLOOP(nt)

#pragma unroll
  for (int mi=0; mi<8; mi++)
#pragma unroll
  for (int nj=0; nj<4; nj++){
    int n = n0 + wc*64 + nj*16 + lr;
#pragma unroll
    for (int r=0; r<4; r++){
      int m = m0 + wr*128 + mi*16 + 4*g + r;
      float val = acc[mi][nj][r] + bias[n];
      if constexpr (EPI==2){
        float gv = 0.5f*val*(1.f + erff(val*0.70710678118654752f));
        ((u16*)outp)[(size_t)m*1024 + n] = f2bf(gv);
      } else {
        ((float*)outp)[(size_t)m*256 + n] = val + res[(size_t)m*256 + n];
      }
    }
  }
}

// ------- O-proj (N=256 full row) + window reverse + residual + fused LN2 -------
__global__ __launch_bounds__(512, 4) void k_oproj(const u16* __restrict__ A, const u16* __restrict__ WF,
                                                  const float* __restrict__ bo, const float* __restrict__ hidden,
                                                  const float* __restrict__ g2, const float* __restrict__ b2v,
                                                  float* __restrict__ hs_out, u16* __restrict__ y2){
  __shared__ __align__(16) u16 As[2][16384];
  __shared__ float part_s[256][4];
  __shared__ float part_q[256][4];
  const int K = 256;
  int tid = threadIdx.x, lane = tid & 63, wid = tid >> 6;
  int g = lane >> 4, lr = lane & 15;
  int wr = wid >> 2, wc = wid & 3;
  int m0 = blockIdx.x*256;
  const int nb16 = 0;
  const int nks = 8;
  const u16* Aw = A + (size_t)m0*K;
  int srow = tid >> 3;
  int scb  = ((tid & 7)*16) ^ ((srow & 7) << 4);
  f32x4 acc[8][4] = {};
  bf16x8 bfr[2][4];

  GLOOP(4)

  float bov[4], g2v[4], b2vv[4];
#pragma unroll
  for (int nj=0;nj<4;nj++){
    int n = wc*64 + nj*16 + lr;
    bov[nj] = bo[n]; g2v[nj] = g2[n]; b2vv[nj] = b2v[n];
  }
#pragma unroll
  for (int mi=0;mi<8;mi++)
#pragma unroll
  for (int r=0;r<4;r++){
    int rowl = wr*128 + mi*16 + 4*g + r;
    int m = m0 + rowl;
    int bi = m >> 12, win = (m >> 6) & 63, p = m & 63;
    int hh = ((win >> 3)*8 + (p >> 3) + 4) & 63;
    int ww = ((win & 7)*8 + (p & 7) + 4) & 63;
    size_t base = ((size_t)bi*4096 + hh*64 + ww)*256;
    float s = 0.f, sq = 0.f;
#pragma unroll
    for (int nj=0;nj<4;nj++){
      int n = wc*64 + nj*16 + lr;
      float val = acc[mi][nj][r] + bov[nj] + hidden[base + n];
      hs_out[base + n] = val;
      acc[mi][nj][r] = val;
      s += val; sq += val*val;
    }
    for (int off=1; off<16; off<<=1){ s += __shfl_xor(s, off); sq += __shfl_xor(sq, off); }
    if (lr == 0){ part_s[rowl][wc] = s; part_q[rowl][wc] = sq; }
  }
  __syncthreads();
#pragma unroll
  for (int mi=0;mi<8;mi++)
#pragma unroll
  for (int r=0;r<4;r++){
    int rowl = wr*128 + mi*16 + 4*g + r;
    int m = m0 + rowl;
    int bi = m >> 12, win = (m >> 6) & 63, p = m & 63;
    int hh = ((win >> 3)*8 + (p >> 3) + 4) & 63;
    int ww = ((win & 7)*8 + (p & 7) + 4) & 63;
    size_t base = ((size_t)bi*4096 + hh*64 + ww)*256;
    float sum = part_s[rowl][0] + part_s[rowl][1] + part_s[rowl][2] + part_s[rowl][3];
    float sqq = part_q[rowl][0] + part_q[rowl][1] + part_q[rowl][2] + part_q[rowl][3];
    float mean = sum*(1.f/256.f);
    float inv = rsqrtf(sqq*(1.f/256.f) - mean*mean + 1e-5f);
#pragma unroll
    for (int nj=0;nj<4;nj++){
      int n = wc*64 + nj*16 + lr;
      y2[base + n] = f2bf((acc[mi][nj][r]-mean)*inv*g2v[nj] + b2vv[nj]);
    }
  }
}

extern "C" void kernel_launch(void* const* d_in, const int* in_sizes, int n_in,
                              void* d_out, int out_size, void* d_ws, size_t ws_size,
                              hipStream_t stream){
  const float* hidden = (const float*)d_in[0];
  const float* ln1g = (const float*)d_in[1];
  const float* ln1b = (const float*)d_in[2];
  const float* wq   = (const float*)d_in[3];
  const float* bq   = (const float*)d_in[4];
  const float* wk   = (const float*)d_in[5];
  const float* bk   = (const float*)d_in[6];
  const float* wv   = (const float*)d_in[7];
  const float* bv   = (const float*)d_in[8];
  const float* btab = (const float*)d_in[9];
  const float* wo   = (const float*)d_in[10];
  const float* bo   = (const float*)d_in[11];
  const float* ln2g = (const float*)d_in[12];
  const float* ln2b = (const float*)d_in[13];
  const float* w1   = (const float*)d_in[14];
  const float* b1   = (const float*)d_in[15];
  const float* w2   = (const float*)d_in[16];
  const float* b2   = (const float*)d_in[17];
  float* out = (float*)d_out;

  char* ws = (char*)d_ws;
  const size_t MB = 1ull << 20;
  u16* xw    = (u16*)ws;                 // [0,64M): attn out
  u16* y1c   = (u16*)(ws + 64*MB);       // [64M,192M): FC1 chunk out
  u16* y2ln  = (u16*)(ws + 192*MB);      // [192M,256M): LN2 out
  u16* fragW = (u16*)(ws + 256*MB);      // QKV weights, fragment-major (384KB)
  u16* woF   = fragW + 196608;           // 16*8*512  = 65536 u16
  u16* w1F   = woF + 65536;              // 64*8*512  = 262144 u16
  u16* w2F   = w1F + 262144;             // 16*32*512 = 262144 u16
  float* bqkv = (float*)(w2F + 262144);
  float* fbias = bqkv + 1024;            // 4*8*64*64 fp32 = 512KB

  // weight prep
  k_fragw<<<768, 256, 0, stream>>>(wq, wk, wv, fragW);
  k_wfrag<<<256, 256, 0, stream>>>(wo, woF, 256, 256);
  k_wfrag<<<1024,256, 0, stream>>>(w1, w1F, 256, 1024);
  k_wfrag<<<1024,256, 0, stream>>>(w2, w2F, 1024, 256);
  k_concat_bias<<<1, 768, 0, stream>>>(bq, bk, bv, bqkv);
  k_bias<<<512, 256, 0, stream>>>(btab, fbias);

  // fused LN1 + shift + QKV + attention -> xw
  k_fattn<<<2048, 512, 0, stream>>>(hidden, ln1g, ln1b, fragW, bqkv, fbias, xw);
  // O-proj + window reverse + residual -> hs (d_out), fused LN2 -> y2ln
  k_oproj<<<512, 512, 0, stream>>>(xw, woF, bo, hidden, ln2g, ln2b, out, y2ln);
  // MLP in 2 M-chunks of 65536 rows
  for (int mc = 0; mc < 2; mc++){
    k_gemm256<2,true><<<dim3(4, 256), 512, 0, stream>>>(y2ln + (size_t)mc*65536*256, w1F, b1, nullptr, y1c, 256);
    k_gemm256<3,false><<<dim3(1, 256), 512, 0, stream>>>(y1c, w2F, b2,
                                                         out + (size_t)mc*65536*256,
                                                         out + (size_t)mc*65536*256, 1024);
  }
}

// Round 10
// 590.753 us; speedup vs baseline: 3.8782x; 3.8782x over previous
//
#include <hip/hip_runtime.h>
#include <hip/hip_bf16.h>
#include <math.h>

typedef unsigned short u16;
typedef __attribute__((ext_vector_type(8))) short bf16x8;
typedef __attribute__((ext_vector_type(8))) unsigned short u16x8;
typedef __attribute__((ext_vector_type(4))) float f32x4;

#define MFMA_BF16 __builtin_amdgcn_mfma_f32_16x16x32_bf16

__device__ __forceinline__ u16 f2bf(float f){
  union { float f; unsigned u; } v; v.f = f;
  unsigned r = v.u + 0x7FFFu + ((v.u >> 16) & 1u);
  return (u16)(r >> 16);
}

__device__ __forceinline__ void gll16(const void* g, void* l){
  __builtin_amdgcn_global_load_lds(
      (const __attribute__((address_space(1))) unsigned int*)g,
      (__attribute__((address_space(3))) unsigned int*)l, 16, 0, 0);
}

__global__ void k_concat_bias(const float* __restrict__ a, const float* __restrict__ b,
                              const float* __restrict__ c, float* __restrict__ o){
  int i = threadIdx.x;  // 768 threads
  o[i] = i < 256 ? a[i] : (i < 512 ? b[i-256] : c[i-512]);
}

// ---- weights -> MFMA-fragment-major: F[n16][ks][lane][8] = W[k][n],
// k = ks*32 + (lane>>4)*8 + j, n = n16*16 + (lane&15)
__global__ __launch_bounds__(256) void k_wfrag(const float* __restrict__ W, u16* __restrict__ F,
                                               int K, int N){
  int idx = blockIdx.x*256 + threadIdx.x;
  int nks = K >> 5;
  int per_n16 = nks << 9;
  int n16 = idx / per_n16; int rem = idx - n16*per_n16;
  int ks = rem >> 9, l8 = rem & 511, lane = l8 >> 3, j = l8 & 7;
  int k = ks*32 + ((lane >> 4) << 3) + j;
  int n = (n16 << 4) + (lane & 15);
  F[idx] = f2bf(W[(size_t)k*N + n]);
}

// ---- QKV weights fragment-major (per head) ----
__global__ __launch_bounds__(256) void k_fragw(const float* __restrict__ wq, const float* __restrict__ wk,
                                               const float* __restrict__ wv, u16* __restrict__ fragW){
  int idx = blockIdx.x*256 + threadIdx.x;    // 3*65536
  int j = idx & 7, lane = (idx >> 3) & 63, nj = (idx >> 9) & 1;
  int ks = (idx >> 10) & 7, h = (idx >> 13) & 7, type = idx >> 16;
  const float* w = type == 0 ? wq : (type == 1 ? wk : wv);
  int k = ks*32 + 8*(lane >> 4) + j;
  int n = h*32 + nj*16 + (lane & 15);
  fragW[idx] = f2bf(w[(size_t)k*256 + n]);
}

// ---- fused rel-pos bias + shift mask, fragment layout: fb2[cls][h][m][lr][nj] ----
__global__ __launch_bounds__(256) void k_bias(const float* __restrict__ btab, float* __restrict__ fb){
  int idx = blockIdx.x*256 + threadIdx.x;   // 4*8*64*64 = 131072
  int nj = idx & 3, lr = (idx >> 2) & 15, m = (idx >> 6) & 63, hh = (idx >> 12) & 7, cls = idx >> 15;
  int n = nj*16 + lr;
  int r1=m>>3, c1=m&7, r2=n>>3, c2=n&7;
  float bv = btab[((r1-r2+7)*15 + (c1-c2+7))*8 + hh];
  int whe = cls>>1, wwe = cls&1;
  int a1 = (whe ? (r1<4?1:2) : 0)*3 + (wwe ? (c1<4?1:2) : 0);
  int a2 = (whe ? (r2<4?1:2) : 0)*3 + (wwe ? (c2<4?1:2) : 0);
  fb[idx] = bv + ((a1!=a2) ? -100.f : 0.f);
}

// ======== FUSED LN1 + QKV-projection + windowed attention ========
__global__ __launch_bounds__(512) void k_fattn(const float* __restrict__ hidden,
    const float* __restrict__ g1, const float* __restrict__ b1f,
    const u16* __restrict__ fragW, const float* __restrict__ bqkv,
    const float* __restrict__ fb, u16* __restrict__ outp)
{
  __shared__ __align__(16) u16 lds[75840];   // 151680 B
  int tid = threadIdx.x, lane = tid & 63, wid = tid >> 6;
  int lg = lane >> 4, lr = lane & 15;
  int gw = blockIdx.x;
  int bi = gw >> 6, win = gw & 63, wh = win >> 3, wwi = win & 7;

  // ---- Phase 1: LN1 + cyclic-shift gather -> xb (chunk-XOR swizzled) ----
  {
    int t = wid*8 + (lane >> 3);
    int j = lane & 7;
    int hh_ = (wh*8 + (t >> 3) + 4) & 63;
    int ww_ = (wwi*8 + (t & 7) + 4) & 63;
    const float4* row = (const float4*)(hidden + ((size_t)bi*4096 + hh_*64 + ww_)*256) + j*8;
    float4 v[8]; float s = 0.f, sq = 0.f;
#pragma unroll
    for (int i=0;i<8;i++){
      v[i] = row[i];
      s  += v[i].x+v[i].y+v[i].z+v[i].w;
      sq += v[i].x*v[i].x+v[i].y*v[i].y+v[i].z*v[i].z+v[i].w*v[i].w;
    }
    s += __shfl_xor(s,1); sq += __shfl_xor(sq,1);
    s += __shfl_xor(s,2); sq += __shfl_xor(sq,2);
    s += __shfl_xor(s,4); sq += __shfl_xor(sq,4);
    float mean = s*(1.f/256.f);
    float inv = rsqrtf(sq*(1.f/256.f) - mean*mean + 1e-5f);
    const float4* gg = (const float4*)g1 + j*8;
    const float4* bb = (const float4*)b1f + j*8;
#pragma unroll
    for (int i2=0;i2<4;i2++){
      float4 a0=v[2*i2], a1=v[2*i2+1];
      float4 g0=gg[2*i2], g1_=gg[2*i2+1];
      float4 b0=bb[2*i2], b1_=bb[2*i2+1];
      u16x8 pk;
      pk[0]=f2bf((a0.x-mean)*inv*g0.x+b0.x); pk[1]=f2bf((a0.y-mean)*inv*g0.y+b0.y);
      pk[2]=f2bf((a0.z-mean)*inv*g0.z+b0.z); pk[3]=f2bf((a0.w-mean)*inv*g0.w+b0.w);
      pk[4]=f2bf((a1.x-mean)*inv*g1_.x+b1_.x); pk[5]=f2bf((a1.y-mean)*inv*g1_.y+b1_.y);
      pk[6]=f2bf((a1.z-mean)*inv*g1_.z+b1_.z); pk[7]=f2bf((a1.w-mean)*inv*g1_.w+b1_.w);
      int c = (j*4+i2) ^ (t & 7);
      *(u16x8*)(&lds[t*256 + c*8]) = pk;
    }
  }
  __syncthreads();

  // ---- Phase 2: mini-GEMM q/k/v for head `wid` (coalesced fragW from L2) ----
  f32x4 qa[4][2]={}, ka[4][2]={}, va[4][2]={};
  __builtin_amdgcn_s_setprio(1);
#pragma unroll
  for (int ks=0; ks<8; ks++){
    bf16x8 af[4];
#pragma unroll
    for (int mi=0;mi<4;mi++){
      int tok = mi*16+lr;
      af[mi] = *(const bf16x8*)(&lds[tok*256 + (((ks*4+lg) ^ (tok&7))*8)]);
    }
    const u16* fq = fragW + ((((size_t)wid)*8 + ks)*2)*512 + lane*8;
#pragma unroll
    for (int nj=0;nj<2;nj++){
      bf16x8 bq_ = *(const bf16x8*)(fq + nj*512);
      bf16x8 bk_ = *(const bf16x8*)(fq + 65536 + nj*512);
      bf16x8 bv_ = *(const bf16x8*)(fq + 131072 + nj*512);
#pragma unroll
      for (int mi=0;mi<4;mi++){
        qa[mi][nj] = MFMA_BF16(af[mi], bq_, qa[mi][nj], 0,0,0);
        ka[mi][nj] = MFMA_BF16(af[mi], bk_, ka[mi][nj], 0,0,0);
        va[mi][nj] = MFMA_BF16(af[mi], bv_, va[mi][nj], 0,0,0);
      }
    }
  }
  __builtin_amdgcn_s_setprio(0);

  // ---- Phase 3: q/k/v -> wave-private LDS ----
  u16* q_l = &lds[16384 + wid*7432];
  u16* k_l = q_l + 2560;
  u16* v_l = q_l + 5120;
  const float scale = 0.1767766952966369f; // 32^-0.5
#pragma unroll
  for (int mi=0;mi<4;mi++)
#pragma unroll
  for (int nj=0;nj<2;nj++){
    int dim = nj*16+lr;
    float bq_ = bqkv[wid*32+dim], bk_ = bqkv[256+wid*32+dim], bv_ = bqkv[512+wid*32+dim];
#pragma unroll
    for (int r=0;r<4;r++){
      int tok = mi*16+4*lg+r;
      q_l[tok*40+dim] = f2bf((qa[mi][nj][r]+bq_)*scale);
      k_l[tok*40+dim] = f2bf(ka[mi][nj][r]+bk_);
    }
    ushort4 vp;
    vp.x = f2bf(va[mi][nj][0]+bv_); vp.y = f2bf(va[mi][nj][1]+bv_);
    vp.z = f2bf(va[mi][nj][2]+bv_); vp.w = f2bf(va[mi][nj][3]+bv_);
    *(ushort4*)(&v_l[dim*72 + mi*16 + 4*lg]) = vp;
  }

  // ---- Phase 4: QK^T + bias/mask + softmax ----
  bf16x8 qf[4], kf[4];
#pragma unroll
  for (int i=0;i<4;i++){
    qf[i] = *(const bf16x8*)(&q_l[(i*16+lr)*40 + 8*lg]);
    kf[i] = *(const bf16x8*)(&k_l[(i*16+lr)*40 + 8*lg]);
  }
  f32x4 acc[4][4] = {};
#pragma unroll
  for (int mi=0;mi<4;mi++)
#pragma unroll
  for (int nj=0;nj<4;nj++)
    acc[mi][nj] = MFMA_BF16(qf[mi], kf[nj], acc[mi][nj], 0,0,0);

  int cls = ((wh==7) ? 2 : 0) | ((wwi==7) ? 1 : 0);
  const float4* fb4 = (const float4*)(fb + (((size_t)cls*8 + wid) << 12));
#pragma unroll
  for (int mi=0;mi<4;mi++)
#pragma unroll
  for (int r=0;r<4;r++){
    int m = mi*16 + 4*lg + r;
    float4 bv4 = fb4[m*16 + lr];
#pragma unroll
    for (int nj=0;nj<4;nj++)
      acc[mi][nj][r] += bv4[nj];
  }
#pragma unroll
  for (int mi=0;mi<4;mi++)
#pragma unroll
  for (int r=0;r<4;r++){
    float mx = fmaxf(fmaxf(acc[mi][0][r], acc[mi][1][r]), fmaxf(acc[mi][2][r], acc[mi][3][r]));
    for (int off=1; off<16; off<<=1) mx = fmaxf(mx, __shfl_xor(mx, off));
    float s = 0.f;
#pragma unroll
    for (int nj=0;nj<4;nj++){ float e = __expf(acc[mi][nj][r]-mx); acc[mi][nj][r]=e; s+=e; }
    for (int off=1; off<16; off<<=1) s += __shfl_xor(s, off);
    float inv = 1.f/s;
#pragma unroll
    for (int nj=0;nj<4;nj++) acc[mi][nj][r] *= inv;
  }

  // P overwrites q_l/k_l: fence (rule 18)
  asm volatile("s_waitcnt lgkmcnt(0)" ::: "memory");
  __builtin_amdgcn_sched_barrier(0);

  u16* P_l = q_l;   // [64][72]
#pragma unroll
  for (int mi=0;mi<4;mi++)
#pragma unroll
  for (int nj=0;nj<4;nj++)
#pragma unroll
  for (int r=0;r<4;r++)
    P_l[(mi*16+4*lg+r)*72 + nj*16 + lr] = f2bf(acc[mi][nj][r]);

  // ---- Phase 5: PV ----
  f32x4 acc2[4][2] = {};
#pragma unroll
  for (int ks=0; ks<2; ks++){
    bf16x8 vf0 = *(const bf16x8*)(&v_l[(lr)*72 + ks*32 + 8*lg]);
    bf16x8 vf1 = *(const bf16x8*)(&v_l[(16+lr)*72 + ks*32 + 8*lg]);
#pragma unroll
    for (int mi=0;mi<4;mi++){
      bf16x8 pf = *(const bf16x8*)(&P_l[(mi*16+lr)*72 + ks*32 + 8*lg]);
      acc2[mi][0] = MFMA_BF16(pf, vf0, acc2[mi][0], 0,0,0);
      acc2[mi][1] = MFMA_BF16(pf, vf1, acc2[mi][1], 0,0,0);
    }
  }

  // ---- Phase 6: out tile -> wave-private LDS [64][40-stride], vectorized store ----
  asm volatile("s_waitcnt lgkmcnt(0)" ::: "memory");
  __builtin_amdgcn_sched_barrier(0);
#pragma unroll
  for (int mi=0;mi<4;mi++)
#pragma unroll
  for (int nt=0;nt<2;nt++)
#pragma unroll
  for (int r=0;r<4;r++)
    q_l[(mi*16+4*lg+r)*40 + nt*16 + lr] = f2bf(acc2[mi][nt][r]);
  asm volatile("s_waitcnt lgkmcnt(0)" ::: "memory");
  __builtin_amdgcn_sched_barrier(0);
#pragma unroll
  for (int p=0;p<4;p++){
    int linear = p*512 + lane*8;
    int tok = linear >> 5, d = linear & 31;
    u16x8 val = *(const u16x8*)(&q_l[tok*40 + d]);
    *(u16x8*)(&outp[((size_t)gw*64 + tok)*256 + wid*32 + d]) = val;
  }
}

// ============ 256x256-tile GEMM: A[M][K] (LDS dbuf) @ Wfrag (L2-direct) ============
// 8 waves (2M x 4N), BK=64, A-only staging (64KB LDS -> 2 blocks/CU),
// B fragments prefetched into registers across barriers.
// vmcnt ledger: at top of iter t, ops newer than A(t) = BLOAD(t)[8] +
// GSTAGE_A(t+1)[4 if exists] -> vmcnt(12) / vmcnt(8) on last iter.
// bfr consumption is register-tracked by the compiler (auto s_waitcnt).
#define GSTAGE_A(buf, k0)                                                \
  _Pragma("unroll")                                                      \
  for (int c = 0; c < 4; c++){                                           \
    int row = c*64 + srow;                                               \
    gll16(Aw + (size_t)row*K + (k0) + (scb>>1), &As[buf][c*4096 + tid*8]); \
  }

#define BLOAD(t)                                                         \
  _Pragma("unroll")                                                      \
  for (int kk = 0; kk < 2; kk++){                                        \
    int ks = ((t)<<1) + kk;                                              \
    _Pragma("unroll")                                                    \
    for (int j = 0; j < 4; j++)                                          \
      bfr[kk][j] = *(const bf16x8*)(WF + ((((size_t)(nb16 + wc*4 + j))*nks + ks)<<9) + lane*8); \
  }

#define GLOOP_BODY(b)                                                    \
  _Pragma("unroll")                                                      \
  for (int kk = 0; kk < 2; kk++){                                        \
    int cbr = (kk*64 + 16*g) ^ ((lr & 7) << 4);                          \
    bf16x8 af[8];                                                        \
    _Pragma("unroll")                                                    \
    for (int i=0;i<8;i++)                                                \
      af[i] = *(const bf16x8*)(&As[b][(wr*128 + i*16 + lr)*64 + (cbr>>1)]); \
    _Pragma("unroll")                                                    \
    for (int mi=0;mi<8;mi++)                                             \
    _Pragma("unroll")                                                    \
    for (int nj=0;nj<4;nj++)                                             \
      acc[mi][nj] = MFMA_BF16(af[mi], bfr[kk][nj], acc[mi][nj], 0,0,0);  \
  }

#define GLOOP(nt)                                                        \
  GSTAGE_A(0, 0)                                                         \
  GSTAGE_A(1, 64)                                                        \
  BLOAD(0)                                                               \
  for (int t = 0; t < (nt); t++){                                        \
    if (t+1 < (nt)) asm volatile("s_waitcnt vmcnt(12)" ::: "memory");    \
    else            asm volatile("s_waitcnt vmcnt(8)" ::: "memory");     \
    __builtin_amdgcn_s_barrier();                                        \
    __builtin_amdgcn_sched_barrier(0);                                   \
    int b = t & 1;                                                       \
    GLOOP_BODY(b)                                                        \
    __builtin_amdgcn_sched_barrier(0);                                   \
    asm volatile("s_waitcnt lgkmcnt(0)" ::: "memory");                   \
    __builtin_amdgcn_s_barrier();                                        \
    __builtin_amdgcn_sched_barrier(0);                                   \
    if (t+1 < (nt)){ BLOAD(t+1) }                                        \
    if (t+2 < (nt)){ GSTAGE_A(b, (t+2)<<6) }                             \
  }

// EPI 2: +b1, exact GELU, bf16 row-major out [m][1024]
// EPI 3: +b2, +hs residual (fp32), fp32 out
template<int EPI, bool SWZ>
__global__ __launch_bounds__(512, 2) void k_gemm256(const u16* __restrict__ A, const u16* __restrict__ WF,
                                                    const float* __restrict__ bias, const float* __restrict__ res,
                                                    void* __restrict__ outp, int K){
  __shared__ __align__(16) u16 As[2][16384];
  int tid = threadIdx.x, lane = tid & 63, wid = tid >> 6;
  int g = lane >> 4, lr = lane & 15;
  int wr = wid >> 2, wc = wid & 3;
  int bx, by;
  if constexpr (SWZ){
    int nwg = gridDim.x*gridDim.y;
    int bid = blockIdx.y*gridDim.x + blockIdx.x;
    int cpx = nwg >> 3;
    int swz = (bid & 7)*cpx + (bid >> 3);
    bx = swz % gridDim.x; by = swz / gridDim.x;
  } else { bx = blockIdx.x; by = blockIdx.y; }
  int m0 = by*256, n0 = bx*256;
  int nb16 = bx << 4;
  int nks = K >> 5;
  const u16* Aw = A + (size_t)m0*K;
  int srow = tid >> 3;
  int scb  = ((tid & 7)*16) ^ ((srow & 7) << 4);
  f32x4 acc[8][4] = {};
  bf16x8 bfr[2][4];
  int nt = K >> 6;

  GLOOP(nt)

#pragma unroll
  for (int mi=0; mi<8; mi++)
#pragma unroll
  for (int nj=0; nj<4; nj++){
    int n = n0 + wc*64 + nj*16 + lr;
#pragma unroll
    for (int r=0; r<4; r++){
      int m = m0 + wr*128 + mi*16 + 4*g + r;
      float val = acc[mi][nj][r] + bias[n];
      if constexpr (EPI==2){
        float gv = 0.5f*val*(1.f + erff(val*0.70710678118654752f));
        ((u16*)outp)[(size_t)m*1024 + n] = f2bf(gv);
      } else {
        ((float*)outp)[(size_t)m*256 + n] = val + res[(size_t)m*256 + n];
      }
    }
  }
}

// ------- O-proj (N=256 full row) + window reverse + residual + fused LN2 -------
__global__ __launch_bounds__(512, 2) void k_oproj(const u16* __restrict__ A, const u16* __restrict__ WF,
                                                  const float* __restrict__ bo, const float* __restrict__ hidden,
                                                  const float* __restrict__ g2, const float* __restrict__ b2v,
                                                  float* __restrict__ hs_out, u16* __restrict__ y2){
  __shared__ __align__(16) u16 As[2][16384];
  __shared__ float part_s[256][4];
  __shared__ float part_q[256][4];
  const int K = 256;
  int tid = threadIdx.x, lane = tid & 63, wid = tid >> 6;
  int g = lane >> 4, lr = lane & 15;
  int wr = wid >> 2, wc = wid & 3;
  int m0 = blockIdx.x*256;
  const int nb16 = 0;
  const int nks = 8;
  const u16* Aw = A + (size_t)m0*K;
  int srow = tid >> 3;
  int scb  = ((tid & 7)*16) ^ ((srow & 7) << 4);
  f32x4 acc[8][4] = {};
  bf16x8 bfr[2][4];

  GLOOP(4)

  float bov[4], g2v[4], b2vv[4];
#pragma unroll
  for (int nj=0;nj<4;nj++){
    int n = wc*64 + nj*16 + lr;
    bov[nj] = bo[n]; g2v[nj] = g2[n]; b2vv[nj] = b2v[n];
  }
#pragma unroll
  for (int mi=0;mi<8;mi++)
#pragma unroll
  for (int r=0;r<4;r++){
    int rowl = wr*128 + mi*16 + 4*g + r;
    int m = m0 + rowl;
    int bi = m >> 12, win = (m >> 6) & 63, p = m & 63;
    int hh = ((win >> 3)*8 + (p >> 3) + 4) & 63;
    int ww = ((win & 7)*8 + (p & 7) + 4) & 63;
    size_t base = ((size_t)bi*4096 + hh*64 + ww)*256;
    float s = 0.f, sq = 0.f;
#pragma unroll
    for (int nj=0;nj<4;nj++){
      int n = wc*64 + nj*16 + lr;
      float val = acc[mi][nj][r] + bov[nj] + hidden[base + n];
      hs_out[base + n] = val;
      acc[mi][nj][r] = val;
      s += val; sq += val*val;
    }
    for (int off=1; off<16; off<<=1){ s += __shfl_xor(s, off); sq += __shfl_xor(sq, off); }
    if (lr == 0){ part_s[rowl][wc] = s; part_q[rowl][wc] = sq; }
  }
  __syncthreads();
#pragma unroll
  for (int mi=0;mi<8;mi++)
#pragma unroll
  for (int r=0;r<4;r++){
    int rowl = wr*128 + mi*16 + 4*g + r;
    int m = m0 + rowl;
    int bi = m >> 12, win = (m >> 6) & 63, p = m & 63;
    int hh = ((win >> 3)*8 + (p >> 3) + 4) & 63;
    int ww = ((win & 7)*8 + (p & 7) + 4) & 63;
    size_t base = ((size_t)bi*4096 + hh*64 + ww)*256;
    float sum = part_s[rowl][0] + part_s[rowl][1] + part_s[rowl][2] + part_s[rowl][3];
    float sqq = part_q[rowl][0] + part_q[rowl][1] + part_q[rowl][2] + part_q[rowl][3];
    float mean = sum*(1.f/256.f);
    float inv = rsqrtf(sqq*(1.f/256.f) - mean*mean + 1e-5f);
#pragma unroll
    for (int nj=0;nj<4;nj++){
      int n = wc*64 + nj*16 + lr;
      y2[base + n] = f2bf((acc[mi][nj][r]-mean)*inv*g2v[nj] + b2vv[nj]);
    }
  }
}

extern "C" void kernel_launch(void* const* d_in, const int* in_sizes, int n_in,
                              void* d_out, int out_size, void* d_ws, size_t ws_size,
                              hipStream_t stream){
  const float* hidden = (const float*)d_in[0];
  const float* ln1g = (const float*)d_in[1];
  const float* ln1b = (const float*)d_in[2];
  const float* wq   = (const float*)d_in[3];
  const float* bq   = (const float*)d_in[4];
  const float* wk   = (const float*)d_in[5];
  const float* bk   = (const float*)d_in[6];
  const float* wv   = (const float*)d_in[7];
  const float* bv   = (const float*)d_in[8];
  const float* btab = (const float*)d_in[9];
  const float* wo   = (const float*)d_in[10];
  const float* bo   = (const float*)d_in[11];
  const float* ln2g = (const float*)d_in[12];
  const float* ln2b = (const float*)d_in[13];
  const float* w1   = (const float*)d_in[14];
  const float* b1   = (const float*)d_in[15];
  const float* w2   = (const float*)d_in[16];
  const float* b2   = (const float*)d_in[17];
  float* out = (float*)d_out;

  char* ws = (char*)d_ws;
  const size_t MB = 1ull << 20;
  u16* xw    = (u16*)ws;                 // [0,64M): attn out
  u16* y1c   = (u16*)(ws + 64*MB);       // [64M,192M): FC1 chunk out
  u16* y2ln  = (u16*)(ws + 192*MB);      // [192M,256M): LN2 out
  u16* fragW = (u16*)(ws + 256*MB);      // QKV weights, fragment-major (384KB)
  u16* woF   = fragW + 196608;           // 16*8*512  = 65536 u16
  u16* w1F   = woF + 65536;              // 64*8*512  = 262144 u16
  u16* w2F   = w1F + 262144;             // 16*32*512 = 262144 u16
  float* bqkv = (float*)(w2F + 262144);
  float* fbias = bqkv + 1024;            // 4*8*64*64 fp32 = 512KB

  // weight prep
  k_fragw<<<768, 256, 0, stream>>>(wq, wk, wv, fragW);
  k_wfrag<<<256, 256, 0, stream>>>(wo, woF, 256, 256);
  k_wfrag<<<1024,256, 0, stream>>>(w1, w1F, 256, 1024);
  k_wfrag<<<1024,256, 0, stream>>>(w2, w2F, 1024, 256);
  k_concat_bias<<<1, 768, 0, stream>>>(bq, bk, bv, bqkv);
  k_bias<<<512, 256, 0, stream>>>(btab, fbias);

  // fused LN1 + shift + QKV + attention -> xw
  k_fattn<<<2048, 512, 0, stream>>>(hidden, ln1g, ln1b, fragW, bqkv, fbias, xw);
  // O-proj + window reverse + residual -> hs (d_out), fused LN2 -> y2ln
  k_oproj<<<512, 512, 0, stream>>>(xw, woF, bo, hidden, ln2g, ln2b, out, y2ln);
  // MLP in 2 M-chunks of 65536 rows
  for (int mc = 0; mc < 2; mc++){
    k_gemm256<2,true><<<dim3(4, 256), 512, 0, stream>>>(y2ln + (size_t)mc*65536*256, w1F, b1, nullptr, y1c, 256);
    k_gemm256<3,false><<<dim3(1, 256), 512, 0, stream>>>(y1c, w2F, b2,
                                                         out + (size_t)mc*65536*256,
                                                         out + (size_t)mc*65536*256, 1024);
  }
}

// Round 11
// 576.988 us; speedup vs baseline: 3.9707x; 1.0239x over previous
//
#include <hip/hip_runtime.h>
#include <hip/hip_bf16.h>
#include <math.h>

typedef unsigned short u16;
typedef __attribute__((ext_vector_type(8))) short bf16x8;
typedef __attribute__((ext_vector_type(8))) unsigned short u16x8;
typedef __attribute__((ext_vector_type(4))) float f32x4;

#define MFMA_BF16 __builtin_amdgcn_mfma_f32_16x16x32_bf16

__device__ __forceinline__ u16 f2bf(float f){
  union { float f; unsigned u; } v; v.f = f;
  unsigned r = v.u + 0x7FFFu + ((v.u >> 16) & 1u);
  return (u16)(r >> 16);
}

__device__ __forceinline__ void gll16(const void* g, void* l){
  __builtin_amdgcn_global_load_lds(
      (const __attribute__((address_space(1))) unsigned int*)g,
      (__attribute__((address_space(3))) unsigned int*)l, 16, 0, 0);
}

__global__ void k_concat_bias(const float* __restrict__ a, const float* __restrict__ b,
                              const float* __restrict__ c, float* __restrict__ o){
  int i = threadIdx.x;  // 768 threads
  o[i] = i < 256 ? a[i] : (i < 512 ? b[i-256] : c[i-512]);
}

// ---- weights -> MFMA-fragment-major: F[n16][ks][lane][8] = W[k][n],
// k = ks*32 + (lane>>4)*8 + j, n = n16*16 + (lane&15)
__global__ __launch_bounds__(256) void k_wfrag(const float* __restrict__ W, u16* __restrict__ F,
                                               int K, int N){
  int idx = blockIdx.x*256 + threadIdx.x;
  int nks = K >> 5;
  int per_n16 = nks << 9;
  int n16 = idx / per_n16; int rem = idx - n16*per_n16;
  int ks = rem >> 9, l8 = rem & 511, lane = l8 >> 3, j = l8 & 7;
  int k = ks*32 + ((lane >> 4) << 3) + j;
  int n = (n16 << 4) + (lane & 15);
  F[idx] = f2bf(W[(size_t)k*N + n]);
}

// ---- QKV weights fragment-major (per head) ----
__global__ __launch_bounds__(256) void k_fragw(const float* __restrict__ wq, const float* __restrict__ wk,
                                               const float* __restrict__ wv, u16* __restrict__ fragW){
  int idx = blockIdx.x*256 + threadIdx.x;    // 3*65536
  int j = idx & 7, lane = (idx >> 3) & 63, nj = (idx >> 9) & 1;
  int ks = (idx >> 10) & 7, h = (idx >> 13) & 7, type = idx >> 16;
  const float* w = type == 0 ? wq : (type == 1 ? wk : wv);
  int k = ks*32 + 8*(lane >> 4) + j;
  int n = h*32 + nj*16 + (lane & 15);
  fragW[idx] = f2bf(w[(size_t)k*256 + n]);
}

// ---- fused rel-pos bias + shift mask, fragment layout: fb2[cls][h][m][lr][nj] ----
__global__ __launch_bounds__(256) void k_bias(const float* __restrict__ btab, float* __restrict__ fb){
  int idx = blockIdx.x*256 + threadIdx.x;   // 4*8*64*64 = 131072
  int nj = idx & 3, lr = (idx >> 2) & 15, m = (idx >> 6) & 63, hh = (idx >> 12) & 7, cls = idx >> 15;
  int n = nj*16 + lr;
  int r1=m>>3, c1=m&7, r2=n>>3, c2=n&7;
  float bv = btab[((r1-r2+7)*15 + (c1-c2+7))*8 + hh];
  int whe = cls>>1, wwe = cls&1;
  int a1 = (whe ? (r1<4?1:2) : 0)*3 + (wwe ? (c1<4?1:2) : 0);
  int a2 = (whe ? (r2<4?1:2) : 0)*3 + (wwe ? (c2<4?1:2) : 0);
  fb[idx] = bv + ((a1!=a2) ? -100.f : 0.f);
}

// ======== FUSED LN1 + QKV-projection + windowed attention ========
// One block per window (2048). 16 waves = 8 heads x 2 token-halves.
// LDS: xb[64][256] swizzled at [0,16384); per-head arena at 16384 + h*7424:
//   k[64][40] (+0), vT[32][72] (+2560), q_s[32][40] (+4864 + s*1280).
//   P_s (32x72): s=0 -> q pair (+4864), s=1 -> k region (+0). Out tile aliases P_s.
__global__ __launch_bounds__(1024) void k_fattn(const float* __restrict__ hidden,
    const float* __restrict__ g1, const float* __restrict__ b1f,
    const u16* __restrict__ fragW, const float* __restrict__ bqkv,
    const float* __restrict__ fb, u16* __restrict__ outp)
{
  __shared__ __align__(16) u16 lds[75776];   // 151552 B
  int tid = threadIdx.x, lane = tid & 63, wid = tid >> 6;
  int lg = lane >> 4, lr = lane & 15;
  int h = wid >> 1, s = wid & 1;
  int gw = blockIdx.x;
  int bi = gw >> 6, win = gw & 63, wh = win >> 3, wwi = win & 7;

  // ---- Phase 1: LN1 + cyclic-shift gather -> xb (chunk-XOR swizzled) ----
  {
    int t = wid*4 + (lane >> 4);           // token 0..63 (16 lanes/token)
    int j = lane & 15;                     // 16-channel slice
    int hh_ = (wh*8 + (t >> 3) + 4) & 63;
    int ww_ = (wwi*8 + (t & 7) + 4) & 63;
    const float4* row = (const float4*)(hidden + ((size_t)bi*4096 + hh_*64 + ww_)*256) + j*4;
    float4 v[4]; float sm = 0.f, sq = 0.f;
#pragma unroll
    for (int i=0;i<4;i++){
      v[i] = row[i];
      sm += v[i].x+v[i].y+v[i].z+v[i].w;
      sq += v[i].x*v[i].x+v[i].y*v[i].y+v[i].z*v[i].z+v[i].w*v[i].w;
    }
    sm += __shfl_xor(sm,1); sq += __shfl_xor(sq,1);
    sm += __shfl_xor(sm,2); sq += __shfl_xor(sq,2);
    sm += __shfl_xor(sm,4); sq += __shfl_xor(sq,4);
    sm += __shfl_xor(sm,8); sq += __shfl_xor(sq,8);
    float mean = sm*(1.f/256.f);
    float inv = rsqrtf(sq*(1.f/256.f) - mean*mean + 1e-5f);
    const float4* gg = (const float4*)g1 + j*4;
    const float4* bb = (const float4*)b1f + j*4;
#pragma unroll
    for (int i2=0;i2<2;i2++){
      float4 a0=v[2*i2], a1=v[2*i2+1];
      float4 g0=gg[2*i2], g1_=gg[2*i2+1];
      float4 b0=bb[2*i2], b1_=bb[2*i2+1];
      u16x8 pk;
      pk[0]=f2bf((a0.x-mean)*inv*g0.x+b0.x); pk[1]=f2bf((a0.y-mean)*inv*g0.y+b0.y);
      pk[2]=f2bf((a0.z-mean)*inv*g0.z+b0.z); pk[3]=f2bf((a0.w-mean)*inv*g0.w+b0.w);
      pk[4]=f2bf((a1.x-mean)*inv*g1_.x+b1_.x); pk[5]=f2bf((a1.y-mean)*inv*g1_.y+b1_.y);
      pk[6]=f2bf((a1.z-mean)*inv*g1_.z+b1_.z); pk[7]=f2bf((a1.w-mean)*inv*g1_.w+b1_.w);
      int c = (j*2 + i2) ^ (t & 7);
      *(u16x8*)(&lds[t*256 + c*8]) = pk;
    }
  }
  __syncthreads();

  // ---- Phase 2: mini-GEMM q/k/v for head h, token half s (fragW from L2) ----
  f32x4 qa[2][2]={}, ka[2][2]={}, va[2][2]={};
  __builtin_amdgcn_s_setprio(1);
#pragma unroll
  for (int ks=0; ks<8; ks++){
    bf16x8 af[2];
#pragma unroll
    for (int mi=0;mi<2;mi++){
      int tok = 32*s + mi*16 + lr;
      af[mi] = *(const bf16x8*)(&lds[tok*256 + (((ks*4+lg) ^ (tok&7))*8)]);
    }
    const u16* fq = fragW + ((((size_t)h)*8 + ks)*2)*512 + lane*8;
#pragma unroll
    for (int nj=0;nj<2;nj++){
      bf16x8 bq_ = *(const bf16x8*)(fq + nj*512);
      bf16x8 bk_ = *(const bf16x8*)(fq + 65536 + nj*512);
      bf16x8 bv_ = *(const bf16x8*)(fq + 131072 + nj*512);
#pragma unroll
      for (int mi=0;mi<2;mi++){
        qa[mi][nj] = MFMA_BF16(af[mi], bq_, qa[mi][nj], 0,0,0);
        ka[mi][nj] = MFMA_BF16(af[mi], bk_, ka[mi][nj], 0,0,0);
        va[mi][nj] = MFMA_BF16(af[mi], bv_, va[mi][nj], 0,0,0);
      }
    }
  }
  __builtin_amdgcn_s_setprio(0);

  // ---- Phase 3: q/k/v -> per-head arena (each wave writes its token half) ----
  u16* hb  = &lds[16384 + h*7424];
  u16* k_h = hb;                    // [64][40]
  u16* v_h = hb + 2560;             // [32 dims][72]
  u16* q_s = hb + 4864 + s*1280;    // [32][40]
  const float scale = 0.1767766952966369f; // 32^-0.5
#pragma unroll
  for (int mi=0;mi<2;mi++)
#pragma unroll
  for (int nj=0;nj<2;nj++){
    int dim = nj*16+lr;
    float bq_ = bqkv[h*32+dim], bk_ = bqkv[256+h*32+dim], bv_ = bqkv[512+h*32+dim];
#pragma unroll
    for (int r=0;r<4;r++){
      int tokl = mi*16+4*lg+r;            // local 0..31
      q_s[tokl*40+dim] = f2bf((qa[mi][nj][r]+bq_)*scale);
      k_h[(32*s+tokl)*40+dim] = f2bf(ka[mi][nj][r]+bk_);
    }
    ushort4 vp;
    vp.x = f2bf(va[mi][nj][0]+bv_); vp.y = f2bf(va[mi][nj][1]+bv_);
    vp.z = f2bf(va[mi][nj][2]+bv_); vp.w = f2bf(va[mi][nj][3]+bv_);
    *(ushort4*)(&v_h[dim*72 + 32*s + mi*16 + 4*lg]) = vp;
  }
  __syncthreads();   // k_h/v_h halves from both waves visible

  // ---- Phase 4: QK^T (32 q-rows x 64 k) + bias/mask + softmax ----
  bf16x8 qf[2], kf[4];
#pragma unroll
  for (int i=0;i<2;i++)
    qf[i] = *(const bf16x8*)(&q_s[(i*16+lr)*40 + 8*lg]);
#pragma unroll
  for (int i=0;i<4;i++)
    kf[i] = *(const bf16x8*)(&k_h[(i*16+lr)*40 + 8*lg]);
  f32x4 acc[2][4] = {};
#pragma unroll
  for (int mi=0;mi<2;mi++)
#pragma unroll
  for (int nj=0;nj<4;nj++)
    acc[mi][nj] = MFMA_BF16(qf[mi], kf[nj], acc[mi][nj], 0,0,0);

  int cls = ((wh==7) ? 2 : 0) | ((wwi==7) ? 1 : 0);
  const float4* fb4 = (const float4*)(fb + (((size_t)cls*8 + h) << 12));
#pragma unroll
  for (int mi=0;mi<2;mi++)
#pragma unroll
  for (int r=0;r<4;r++){
    int m = 32*s + mi*16 + 4*lg + r;
    float4 bv4 = fb4[m*16 + lr];
#pragma unroll
    for (int nj=0;nj<4;nj++)
      acc[mi][nj][r] += bv4[nj];
  }
#pragma unroll
  for (int mi=0;mi<2;mi++)
#pragma unroll
  for (int r=0;r<4;r++){
    float mx = fmaxf(fmaxf(acc[mi][0][r], acc[mi][1][r]), fmaxf(acc[mi][2][r], acc[mi][3][r]));
    for (int off=1; off<16; off<<=1) mx = fmaxf(mx, __shfl_xor(mx, off));
    float sum = 0.f;
#pragma unroll
    for (int nj=0;nj<4;nj++){ float e = __expf(acc[mi][nj][r]-mx); acc[mi][nj][r]=e; sum+=e; }
    for (int off=1; off<16; off<<=1) sum += __shfl_xor(sum, off);
    float inv = 1.f/sum;
#pragma unroll
    for (int nj=0;nj<4;nj++) acc[mi][nj][r] *= inv;
  }

  // P overwrites k/q regions that the PARTNER wave reads in its QK^T -> block sync.
  __syncthreads();

  u16* P_s = s ? hb : (hb + 4864);   // [32][72], wave-private
#pragma unroll
  for (int mi=0;mi<2;mi++)
#pragma unroll
  for (int nj=0;nj<4;nj++)
#pragma unroll
  for (int r=0;r<4;r++)
    P_s[(mi*16+4*lg+r)*72 + nj*16 + lr] = f2bf(acc[mi][nj][r]);

  // ---- Phase 5: PV (own 32 rows x full V) ----
  f32x4 acc2[2][2] = {};
#pragma unroll
  for (int ks=0; ks<2; ks++){
    bf16x8 vf0 = *(const bf16x8*)(&v_h[(lr)*72 + ks*32 + 8*lg]);
    bf16x8 vf1 = *(const bf16x8*)(&v_h[(16+lr)*72 + ks*32 + 8*lg]);
#pragma unroll
    for (int mi=0;mi<2;mi++){
      bf16x8 pf = *(const bf16x8*)(&P_s[(mi*16+lr)*72 + ks*32 + 8*lg]);
      acc2[mi][0] = MFMA_BF16(pf, vf0, acc2[mi][0], 0,0,0);
      acc2[mi][1] = MFMA_BF16(pf, vf1, acc2[mi][1], 0,0,0);
    }
  }

  // ---- Phase 6: out tile -> own P region [32][40], then vectorized store ----
#pragma unroll
  for (int mi=0;mi<2;mi++)
#pragma unroll
  for (int nt=0;nt<2;nt++)
#pragma unroll
  for (int r=0;r<4;r++)
    P_s[(mi*16+4*lg+r)*40 + nt*16 + lr] = f2bf(acc2[mi][nt][r]);
#pragma unroll
  for (int p=0;p<2;p++){
    int linear = p*512 + lane*8;       // u16 index within 32x32 tile
    int tokl = linear >> 5, d = linear & 31;
    u16x8 val = *(const u16x8*)(&P_s[tokl*40 + d]);
    *(u16x8*)(&outp[((size_t)gw*64 + 32*s + tokl)*256 + h*32 + d]) = val;
  }
}

// ============ 256x256-tile GEMM: A[M][K] (LDS dbuf) @ Wfrag (L2-direct) ============
// 8 waves (2M x 4N), BK=64, A-only staging (64KB LDS -> 2 blocks/CU),
// B fragments prefetched into registers across barriers.
// vmcnt ledger: at top of iter t, ops newer than A(t) = BLOAD(t)[8] +
// GSTAGE_A(t+1)[4 if exists] -> vmcnt(12) / vmcnt(8) on last iter.
#define GSTAGE_A(buf, k0)                                                \
  _Pragma("unroll")                                                      \
  for (int c = 0; c < 4; c++){                                           \
    int row = c*64 + srow;                                               \
    gll16(Aw + (size_t)row*K + (k0) + (scb>>1), &As[buf][c*4096 + tid*8]); \
  }

#define BLOAD(t)                                                         \
  _Pragma("unroll")                                                      \
  for (int kk = 0; kk < 2; kk++){                                        \
    int ks = ((t)<<1) + kk;                                              \
    _Pragma("unroll")                                                    \
    for (int j = 0; j < 4; j++)                                          \
      bfr[kk][j] = *(const bf16x8*)(WF + ((((size_t)(nb16 + wc*4 + j))*nks + ks)<<9) + lane*8); \
  }

#define GLOOP_BODY(b)                                                    \
  _Pragma("unroll")                                                      \
  for (int kk = 0; kk < 2; kk++){                                        \
    int cbr = (kk*64 + 16*g) ^ ((lr & 7) << 4);                          \
    bf16x8 af[8];                                                        \
    _Pragma("unroll")                                                    \
    for (int i=0;i<8;i++)                                                \
      af[i] = *(const bf16x8*)(&As[b][(wr*128 + i*16 + lr)*64 + (cbr>>1)]); \
    _Pragma("unroll")                                                    \
    for (int mi=0;mi<8;mi++)                                             \
    _Pragma("unroll")                                                    \
    for (int nj=0;nj<4;nj++)                                             \
      acc[mi][nj] = MFMA_BF16(af[mi], bfr[kk][nj], acc[mi][nj], 0,0,0);  \
  }

#define GLOOP(nt)                                                        \
  GSTAGE_A(0, 0)                                                         \
  GSTAGE_A(1, 64)                                                        \
  BLOAD(0)                                                               \
  for (int t = 0; t < (nt); t++){                                        \
    if (t+1 < (nt)) asm volatile("s_waitcnt vmcnt(12)" ::: "memory");    \
    else            asm volatile("s_waitcnt vmcnt(8)" ::: "memory");     \
    __builtin_amdgcn_s_barrier();                                        \
    __builtin_amdgcn_sched_barrier(0);                                   \
    int b = t & 1;                                                       \
    GLOOP_BODY(b)                                                        \
    __builtin_amdgcn_sched_barrier(0);                                   \
    asm volatile("s_waitcnt lgkmcnt(0)" ::: "memory");                   \
    __builtin_amdgcn_s_barrier();                                        \
    __builtin_amdgcn_sched_barrier(0);                                   \
    if (t+1 < (nt)){ BLOAD(t+1) }                                        \
    if (t+2 < (nt)){ GSTAGE_A(b, (t+2)<<6) }                             \
  }

// EPI 2: +b1, exact GELU, bf16 row-major out [m][1024]
// EPI 3: +b2, +hs residual (fp32), fp32 out
template<int EPI, bool SWZ>
__global__ __launch_bounds__(512, 2) void k_gemm256(const u16* __restrict__ A, const u16* __restrict__ WF,
                                                    const float* __restrict__ bias, const float* __restrict__ res,
                                                    void* __restrict__ outp, int K){
  __shared__ __align__(16) u16 As[2][16384];
  int tid = threadIdx.x, lane = tid & 63, wid = tid >> 6;
  int g = lane >> 4, lr = lane & 15;
  int wr = wid >> 2, wc = wid & 3;
  int bx, by;
  if constexpr (SWZ){
    int nwg = gridDim.x*gridDim.y;
    int bid = blockIdx.y*gridDim.x + blockIdx.x;
    int cpx = nwg >> 3;
    int swz = (bid & 7)*cpx + (bid >> 3);
    bx = swz % gridDim.x; by = swz / gridDim.x;
  } else { bx = blockIdx.x; by = blockIdx.y; }
  int m0 = by*256, n0 = bx*256;
  int nb16 = bx << 4;
  int nks = K >> 5;
  const u16* Aw = A + (size_t)m0*K;
  int srow = tid >> 3;
  int scb  = ((tid & 7)*16) ^ ((srow & 7) << 4);
  f32x4 acc[8][4] = {};
  bf16x8 bfr[2][4];
  int nt = K >> 6;

  GLOOP(nt)

#pragma unroll
  for (int mi=0; mi<8; mi++)
#pragma unroll
  for (int nj=0; nj<4; nj++){
    int n = n0 + wc*64 + nj*16 + lr;
#pragma unroll
    for (int r=0; r<4; r++){
      int m = m0 + wr*128 + mi*16 + 4*g + r;
      float val = acc[mi][nj][r] + bias[n];
      if constexpr (EPI==2){
        float gv = 0.5f*val*(1.f + erff(val*0.70710678118654752f));
        ((u16*)outp)[(size_t)m*1024 + n] = f2bf(gv);
      } else {
        ((float*)outp)[(size_t)m*256 + n] = val + res[(size_t)m*256 + n];
      }
    }
  }
}

// ------- O-proj (N=256 full row) + window reverse + residual + fused LN2 -------
__global__ __launch_bounds__(512, 2) void k_oproj(const u16* __restrict__ A, const u16* __restrict__ WF,
                                                  const float* __restrict__ bo, const float* __restrict__ hidden,
                                                  const float* __restrict__ g2, const float* __restrict__ b2v,
                                                  float* __restrict__ hs_out, u16* __restrict__ y2){
  __shared__ __align__(16) u16 As[2][16384];
  __shared__ float part_s[256][4];
  __shared__ float part_q[256][4];
  const int K = 256;
  int tid = threadIdx.x, lane = tid & 63, wid = tid >> 6;
  int g = lane >> 4, lr = lane & 15;
  int wr = wid >> 2, wc = wid & 3;
  int m0 = blockIdx.x*256;
  const int nb16 = 0;
  const int nks = 8;
  const u16* Aw = A + (size_t)m0*K;
  int srow = tid >> 3;
  int scb  = ((tid & 7)*16) ^ ((srow & 7) << 4);
  f32x4 acc[8][4] = {};
  bf16x8 bfr[2][4];

  GLOOP(4)

  float bov[4], g2v[4], b2vv[4];
#pragma unroll
  for (int nj=0;nj<4;nj++){
    int n = wc*64 + nj*16 + lr;
    bov[nj] = bo[n]; g2v[nj] = g2[n]; b2vv[nj] = b2v[n];
  }
#pragma unroll
  for (int mi=0;mi<8;mi++)
#pragma unroll
  for (int r=0;r<4;r++){
    int rowl = wr*128 + mi*16 + 4*g + r;
    int m = m0 + rowl;
    int bi = m >> 12, win = (m >> 6) & 63, p = m & 63;
    int hh = ((win >> 3)*8 + (p >> 3) + 4) & 63;
    int ww = ((win & 7)*8 + (p & 7) + 4) & 63;
    size_t base = ((size_t)bi*4096 + hh*64 + ww)*256;
    float s = 0.f, sq = 0.f;
#pragma unroll
    for (int nj=0;nj<4;nj++){
      int n = wc*64 + nj*16 + lr;
      float val = acc[mi][nj][r] + bov[nj] + hidden[base + n];
      hs_out[base + n] = val;
      acc[mi][nj][r] = val;
      s += val; sq += val*val;
    }
    for (int off=1; off<16; off<<=1){ s += __shfl_xor(s, off); sq += __shfl_xor(sq, off); }
    if (lr == 0){ part_s[rowl][wc] = s; part_q[rowl][wc] = sq; }
  }
  __syncthreads();
#pragma unroll
  for (int mi=0;mi<8;mi++)
#pragma unroll
  for (int r=0;r<4;r++){
    int rowl = wr*128 + mi*16 + 4*g + r;
    int m = m0 + rowl;
    int bi = m >> 12, win = (m >> 6) & 63, p = m & 63;
    int hh = ((win >> 3)*8 + (p >> 3) + 4) & 63;
    int ww = ((win & 7)*8 + (p & 7) + 4) & 63;
    size_t base = ((size_t)bi*4096 + hh*64 + ww)*256;
    float sum = part_s[rowl][0] + part_s[rowl][1] + part_s[rowl][2] + part_s[rowl][3];
    float sqq = part_q[rowl][0] + part_q[rowl][1] + part_q[rowl][2] + part_q[rowl][3];
    float mean = sum*(1.f/256.f);
    float inv = rsqrtf(sqq*(1.f/256.f) - mean*mean + 1e-5f);
#pragma unroll
    for (int nj=0;nj<4;nj++){
      int n = wc*64 + nj*16 + lr;
      y2[base + n] = f2bf((acc[mi][nj][r]-mean)*inv*g2v[nj] + b2vv[nj]);
    }
  }
}

extern "C" void kernel_launch(void* const* d_in, const int* in_sizes, int n_in,
                              void* d_out, int out_size, void* d_ws, size_t ws_size,
                              hipStream_t stream){
  const float* hidden = (const float*)d_in[0];
  const float* ln1g = (const float*)d_in[1];
  const float* ln1b = (const float*)d_in[2];
  const float* wq   = (const float*)d_in[3];
  const float* bq   = (const float*)d_in[4];
  const float* wk   = (const float*)d_in[5];
  const float* bk   = (const float*)d_in[6];
  const float* wv   = (const float*)d_in[7];
  const float* bv   = (const float*)d_in[8];
  const float* btab = (const float*)d_in[9];
  const float* wo   = (const float*)d_in[10];
  const float* bo   = (const float*)d_in[11];
  const float* ln2g = (const float*)d_in[12];
  const float* ln2b = (const float*)d_in[13];
  const float* w1   = (const float*)d_in[14];
  const float* b1   = (const float*)d_in[15];
  const float* w2   = (const float*)d_in[16];
  const float* b2   = (const float*)d_in[17];
  float* out = (float*)d_out;

  char* ws = (char*)d_ws;
  const size_t MB = 1ull << 20;
  u16* xw    = (u16*)ws;                 // [0,64M): attn out
  u16* y1c   = (u16*)(ws + 64*MB);       // [64M,192M): FC1 chunk out
  u16* y2ln  = (u16*)(ws + 192*MB);      // [192M,256M): LN2 out
  u16* fragW = (u16*)(ws + 256*MB);      // QKV weights, fragment-major (384KB)
  u16* woF   = fragW + 196608;           // 16*8*512  = 65536 u16
  u16* w1F   = woF + 65536;              // 64*8*512  = 262144 u16
  u16* w2F   = w1F + 262144;             // 16*32*512 = 262144 u16
  float* bqkv = (float*)(w2F + 262144);
  float* fbias = bqkv + 1024;            // 4*8*64*64 fp32 = 512KB

  // weight prep
  k_fragw<<<768, 256, 0, stream>>>(wq, wk, wv, fragW);
  k_wfrag<<<256, 256, 0, stream>>>(wo, woF, 256, 256);
  k_wfrag<<<1024,256, 0, stream>>>(w1, w1F, 256, 1024);
  k_wfrag<<<1024,256, 0, stream>>>(w2, w2F, 1024, 256);
  k_concat_bias<<<1, 768, 0, stream>>>(bq, bk, bv, bqkv);
  k_bias<<<512, 256, 0, stream>>>(btab, fbias);

  // fused LN1 + shift + QKV + attention -> xw (16 waves, 2 waves/head)
  k_fattn<<<2048, 1024, 0, stream>>>(hidden, ln1g, ln1b, fragW, bqkv, fbias, xw);
  // O-proj + window reverse + residual -> hs (d_out), fused LN2 -> y2ln
  k_oproj<<<512, 512, 0, stream>>>(xw, woF, bo, hidden, ln2g, ln2b, out, y2ln);
  // MLP in 2 M-chunks of 65536 rows
  for (int mc = 0; mc < 2; mc++){
    k_gemm256<2,true><<<dim3(4, 256), 512, 0, stream>>>(y2ln + (size_t)mc*65536*256, w1F, b1, nullptr, y1c, 256);
    k_gemm256<3,false><<<dim3(1, 256), 512, 0, stream>>>(y1c, w2F, b2,
                                                         out + (size_t)mc*65536*256,
                                                         out + (size_t)mc*65536*256, 1024);
  }
}

// Round 12
// 559.316 us; speedup vs baseline: 4.0961x; 1.0316x over previous
//
#include <hip/hip_runtime.h>
#include <hip/hip_bf16.h>
#include <math.h>

typedef unsigned short u16;
typedef __attribute__((ext_vector_type(8))) short bf16x8;
typedef __attribute__((ext_vector_type(8))) unsigned short u16x8;
typedef __attribute__((ext_vector_type(4))) float f32x4;

#define MFMA_BF16 __builtin_amdgcn_mfma_f32_16x16x32_bf16

__device__ __forceinline__ u16 f2bf(float f){
  union { float f; unsigned u; } v; v.f = f;
  unsigned r = v.u + 0x7FFFu + ((v.u >> 16) & 1u);
  return (u16)(r >> 16);
}

__device__ __forceinline__ void gll16(const void* g, void* l){
  __builtin_amdgcn_global_load_lds(
      (const __attribute__((address_space(1))) unsigned int*)g,
      (__attribute__((address_space(3))) unsigned int*)l, 16, 0, 0);
}

__global__ void k_concat_bias(const float* __restrict__ a, const float* __restrict__ b,
                              const float* __restrict__ c, float* __restrict__ o){
  int i = threadIdx.x;  // 768 threads
  o[i] = i < 256 ? a[i] : (i < 512 ? b[i-256] : c[i-512]);
}

// ---- weights -> MFMA-fragment-major: F[n16][ks][lane][8] = W[k][n],
// k = ks*32 + (lane>>4)*8 + j, n = n16*16 + (lane&15)
__global__ __launch_bounds__(256) void k_wfrag(const float* __restrict__ W, u16* __restrict__ F,
                                               int K, int N){
  int idx = blockIdx.x*256 + threadIdx.x;
  int nks = K >> 5;
  int per_n16 = nks << 9;
  int n16 = idx / per_n16; int rem = idx - n16*per_n16;
  int ks = rem >> 9, l8 = rem & 511, lane = l8 >> 3, j = l8 & 7;
  int k = ks*32 + ((lane >> 4) << 3) + j;
  int n = (n16 << 4) + (lane & 15);
  F[idx] = f2bf(W[(size_t)k*N + n]);
}

// ---- QKV weights fragment-major (per head) ----
__global__ __launch_bounds__(256) void k_fragw(const float* __restrict__ wq, const float* __restrict__ wk,
                                               const float* __restrict__ wv, u16* __restrict__ fragW){
  int idx = blockIdx.x*256 + threadIdx.x;    // 3*65536
  int j = idx & 7, lane = (idx >> 3) & 63, nj = (idx >> 9) & 1;
  int ks = (idx >> 10) & 7, h = (idx >> 13) & 7, type = idx >> 16;
  const float* w = type == 0 ? wq : (type == 1 ? wk : wv);
  int k = ks*32 + 8*(lane >> 4) + j;
  int n = h*32 + nj*16 + (lane & 15);
  fragW[idx] = f2bf(w[(size_t)k*256 + n]);
}

// ---- fused rel-pos bias + shift mask, fragment layout: fb2[cls][h][m][lr][nj] ----
__global__ __launch_bounds__(256) void k_bias(const float* __restrict__ btab, float* __restrict__ fb){
  int idx = blockIdx.x*256 + threadIdx.x;   // 4*8*64*64 = 131072
  int nj = idx & 3, lr = (idx >> 2) & 15, m = (idx >> 6) & 63, hh = (idx >> 12) & 7, cls = idx >> 15;
  int n = nj*16 + lr;
  int r1=m>>3, c1=m&7, r2=n>>3, c2=n&7;
  float bv = btab[((r1-r2+7)*15 + (c1-c2+7))*8 + hh];
  int whe = cls>>1, wwe = cls&1;
  int a1 = (whe ? (r1<4?1:2) : 0)*3 + (wwe ? (c1<4?1:2) : 0);
  int a2 = (whe ? (r2<4?1:2) : 0)*3 + (wwe ? (c2<4?1:2) : 0);
  fb[idx] = bv + ((a1!=a2) ? -100.f : 0.f);
}

// ======== FUSED LN1 + QKV + windowed attention + O-proj + residual + LN2 ========
// One block per window (2048). 16 waves = 8 heads x 2 token-halves.
// LDS: xb[64][256] swizzled at [0,16384) (reused as attn-out tile after phase 2);
// per-head arena at 16384 + h*7424: k[64][40], vT[32][72], q_s[32][40];
// P_s aliases q/k regions after softmax; LN2 partials alias arena after PV.
__global__ __launch_bounds__(1024) void k_fattn(const float* __restrict__ hidden,
    const float* __restrict__ g1, const float* __restrict__ b1f,
    const u16* __restrict__ fragW, const float* __restrict__ bqkv,
    const float* __restrict__ fb, const u16* __restrict__ woF,
    const float* __restrict__ bo, const float* __restrict__ g2,
    const float* __restrict__ b2v,
    float* __restrict__ hs_out, u16* __restrict__ y2)
{
  __shared__ __align__(16) u16 lds[75776];   // 151552 B
  int tid = threadIdx.x, lane = tid & 63, wid = tid >> 6;
  int lg = lane >> 4, lr = lane & 15;
  int h = wid >> 1, s = wid & 1;
  int gw = blockIdx.x;
  int bi = gw >> 6, win = gw & 63, wh = win >> 3, wwi = win & 7;

  // ---- Phase 1: LN1 + cyclic-shift gather -> xb (chunk-XOR swizzled) ----
  {
    int t = wid*4 + (lane >> 4);           // token 0..63 (16 lanes/token)
    int j = lane & 15;                     // 16-channel slice
    int hh_ = (wh*8 + (t >> 3) + 4) & 63;
    int ww_ = (wwi*8 + (t & 7) + 4) & 63;
    const float4* row = (const float4*)(hidden + ((size_t)bi*4096 + hh_*64 + ww_)*256) + j*4;
    float4 v[4]; float sm = 0.f, sq = 0.f;
#pragma unroll
    for (int i=0;i<4;i++){
      v[i] = row[i];
      sm += v[i].x+v[i].y+v[i].z+v[i].w;
      sq += v[i].x*v[i].x+v[i].y*v[i].y+v[i].z*v[i].z+v[i].w*v[i].w;
    }
    sm += __shfl_xor(sm,1); sq += __shfl_xor(sq,1);
    sm += __shfl_xor(sm,2); sq += __shfl_xor(sq,2);
    sm += __shfl_xor(sm,4); sq += __shfl_xor(sq,4);
    sm += __shfl_xor(sm,8); sq += __shfl_xor(sq,8);
    float mean = sm*(1.f/256.f);
    float inv = rsqrtf(sq*(1.f/256.f) - mean*mean + 1e-5f);
    const float4* gg = (const float4*)g1 + j*4;
    const float4* bb = (const float4*)b1f + j*4;
#pragma unroll
    for (int i2=0;i2<2;i2++){
      float4 a0=v[2*i2], a1=v[2*i2+1];
      float4 g0=gg[2*i2], g1_=gg[2*i2+1];
      float4 b0=bb[2*i2], b1_=bb[2*i2+1];
      u16x8 pk;
      pk[0]=f2bf((a0.x-mean)*inv*g0.x+b0.x); pk[1]=f2bf((a0.y-mean)*inv*g0.y+b0.y);
      pk[2]=f2bf((a0.z-mean)*inv*g0.z+b0.z); pk[3]=f2bf((a0.w-mean)*inv*g0.w+b0.w);
      pk[4]=f2bf((a1.x-mean)*inv*g1_.x+b1_.x); pk[5]=f2bf((a1.y-mean)*inv*g1_.y+b1_.y);
      pk[6]=f2bf((a1.z-mean)*inv*g1_.z+b1_.z); pk[7]=f2bf((a1.w-mean)*inv*g1_.w+b1_.w);
      int c = (j*2 + i2) ^ (t & 7);
      *(u16x8*)(&lds[t*256 + c*8]) = pk;
    }
  }
  __syncthreads();

  // ---- Phase 2: mini-GEMM q/k/v for head h, token half s (fragW from L2) ----
  f32x4 qa[2][2]={}, ka[2][2]={}, va[2][2]={};
  __builtin_amdgcn_s_setprio(1);
#pragma unroll
  for (int ks=0; ks<8; ks++){
    bf16x8 af[2];
#pragma unroll
    for (int mi=0;mi<2;mi++){
      int tok = 32*s + mi*16 + lr;
      af[mi] = *(const bf16x8*)(&lds[tok*256 + (((ks*4+lg) ^ (tok&7))*8)]);
    }
    const u16* fq = fragW + ((((size_t)h)*8 + ks)*2)*512 + lane*8;
#pragma unroll
    for (int nj=0;nj<2;nj++){
      bf16x8 bq_ = *(const bf16x8*)(fq + nj*512);
      bf16x8 bk_ = *(const bf16x8*)(fq + 65536 + nj*512);
      bf16x8 bv_ = *(const bf16x8*)(fq + 131072 + nj*512);
#pragma unroll
      for (int mi=0;mi<2;mi++){
        qa[mi][nj] = MFMA_BF16(af[mi], bq_, qa[mi][nj], 0,0,0);
        ka[mi][nj] = MFMA_BF16(af[mi], bk_, ka[mi][nj], 0,0,0);
        va[mi][nj] = MFMA_BF16(af[mi], bv_, va[mi][nj], 0,0,0);
      }
    }
  }
  __builtin_amdgcn_s_setprio(0);

  // ---- Phase 3: q/k/v -> per-head arena (each wave writes its token half) ----
  u16* hb  = &lds[16384 + h*7424];
  u16* k_h = hb;                    // [64][40]
  u16* v_h = hb + 2560;             // [32 dims][72]
  u16* q_s = hb + 4864 + s*1280;    // [32][40]
  const float scale = 0.1767766952966369f; // 32^-0.5
#pragma unroll
  for (int mi=0;mi<2;mi++)
#pragma unroll
  for (int nj=0;nj<2;nj++){
    int dim = nj*16+lr;
    float bq_ = bqkv[h*32+dim], bk_ = bqkv[256+h*32+dim], bv_ = bqkv[512+h*32+dim];
#pragma unroll
    for (int r=0;r<4;r++){
      int tokl = mi*16+4*lg+r;            // local 0..31
      q_s[tokl*40+dim] = f2bf((qa[mi][nj][r]+bq_)*scale);
      k_h[(32*s+tokl)*40+dim] = f2bf(ka[mi][nj][r]+bk_);
    }
    ushort4 vp;
    vp.x = f2bf(va[mi][nj][0]+bv_); vp.y = f2bf(va[mi][nj][1]+bv_);
    vp.z = f2bf(va[mi][nj][2]+bv_); vp.w = f2bf(va[mi][nj][3]+bv_);
    *(ushort4*)(&v_h[dim*72 + 32*s + mi*16 + 4*lg]) = vp;
  }
  __syncthreads();   // k_h/v_h halves from both waves visible

  // ---- Phase 4: QK^T (32 q-rows x 64 k) + bias/mask + softmax ----
  bf16x8 qf[2], kf[4];
#pragma unroll
  for (int i=0;i<2;i++)
    qf[i] = *(const bf16x8*)(&q_s[(i*16+lr)*40 + 8*lg]);
#pragma unroll
  for (int i=0;i<4;i++)
    kf[i] = *(const bf16x8*)(&k_h[(i*16+lr)*40 + 8*lg]);
  f32x4 acc[2][4] = {};
#pragma unroll
  for (int mi=0;mi<2;mi++)
#pragma unroll
  for (int nj=0;nj<4;nj++)
    acc[mi][nj] = MFMA_BF16(qf[mi], kf[nj], acc[mi][nj], 0,0,0);

  int cls = ((wh==7) ? 2 : 0) | ((wwi==7) ? 1 : 0);
  const float4* fb4 = (const float4*)(fb + (((size_t)cls*8 + h) << 12));
#pragma unroll
  for (int mi=0;mi<2;mi++)
#pragma unroll
  for (int r=0;r<4;r++){
    int m = 32*s + mi*16 + 4*lg + r;
    float4 bv4 = fb4[m*16 + lr];
#pragma unroll
    for (int nj=0;nj<4;nj++)
      acc[mi][nj][r] += bv4[nj];
  }
#pragma unroll
  for (int mi=0;mi<2;mi++)
#pragma unroll
  for (int r=0;r<4;r++){
    float mx = fmaxf(fmaxf(acc[mi][0][r], acc[mi][1][r]), fmaxf(acc[mi][2][r], acc[mi][3][r]));
    for (int off=1; off<16; off<<=1) mx = fmaxf(mx, __shfl_xor(mx, off));
    float sum = 0.f;
#pragma unroll
    for (int nj=0;nj<4;nj++){ float e = __expf(acc[mi][nj][r]-mx); acc[mi][nj][r]=e; sum+=e; }
    for (int off=1; off<16; off<<=1) sum += __shfl_xor(sum, off);
    float inv = 1.f/sum;
#pragma unroll
    for (int nj=0;nj<4;nj++) acc[mi][nj][r] *= inv;
  }

  // P overwrites k/q regions read by partner's QK^T; also all phase-2 xb reads
  // must be done before the out-tile overwrites xb below -> block sync.
  __syncthreads();

  u16* P_s = s ? hb : (hb + 4864);   // [32][72], wave-private
#pragma unroll
  for (int mi=0;mi<2;mi++)
#pragma unroll
  for (int nj=0;nj<4;nj++)
#pragma unroll
  for (int r=0;r<4;r++)
    P_s[(mi*16+4*lg+r)*72 + nj*16 + lr] = f2bf(acc[mi][nj][r]);

  // ---- Phase 5: PV (own 32 rows x full V) ----
  f32x4 acc2[2][2] = {};
#pragma unroll
  for (int ks=0; ks<2; ks++){
    bf16x8 vf0 = *(const bf16x8*)(&v_h[(lr)*72 + ks*32 + 8*lg]);
    bf16x8 vf1 = *(const bf16x8*)(&v_h[(16+lr)*72 + ks*32 + 8*lg]);
#pragma unroll
    for (int mi=0;mi<2;mi++){
      bf16x8 pf = *(const bf16x8*)(&P_s[(mi*16+lr)*72 + ks*32 + 8*lg]);
      acc2[mi][0] = MFMA_BF16(pf, vf0, acc2[mi][0], 0,0,0);
      acc2[mi][1] = MFMA_BF16(pf, vf1, acc2[mi][1], 0,0,0);
    }
  }

  // ---- Phase 6: attn-out tile -> xb (same chunk-XOR swizzle) ----
#pragma unroll
  for (int mi=0;mi<2;mi++)
#pragma unroll
  for (int nt=0;nt<2;nt++)
#pragma unroll
  for (int r=0;r<4;r++){
    int row = 32*s + mi*16 + 4*lg + r;
    int chunk = (4*h + 2*nt + (lr>>3)) ^ (row & 7);
    lds[row*256 + chunk*8 + (lr&7)] = f2bf(acc2[mi][nt][r]);
  }
  __syncthreads();   // full 64x256 out tile visible; arenas now dead

  // ---- Phase 7: O-proj mini-GEMM: rows 32s..+31, cols 32h..+31, K=256 ----
  f32x4 po[2][2] = {};
  __builtin_amdgcn_s_setprio(1);
#pragma unroll
  for (int ks=0; ks<8; ks++){
    bf16x8 af2[2];
#pragma unroll
    for (int mi=0;mi<2;mi++){
      int row = 32*s + mi*16 + lr;
      af2[mi] = *(const bf16x8*)(&lds[row*256 + (((ks*4+lg) ^ (row&7))*8)]);
    }
#pragma unroll
    for (int nj=0;nj<2;nj++){
      bf16x8 bw = *(const bf16x8*)(woF + (((size_t)(2*h+nj))*8 + ks)*512 + lane*8);
#pragma unroll
      for (int mi=0;mi<2;mi++)
        po[mi][nj] = MFMA_BF16(af2[mi], bw, po[mi][nj], 0,0,0);
    }
  }
  __builtin_amdgcn_s_setprio(0);

  // ---- Phase 8: +bo, window-reverse residual, hs -> d_out, LN2 partials ----
  float* part_s = (float*)&lds[16384];          // [64][8]
  float* part_q = (float*)&lds[16384 + 1024];   // [64][8]
  float bov[2], g2v[2], b2vv[2];
#pragma unroll
  for (int nj=0;nj<2;nj++){
    int n = 32*h + nj*16 + lr;
    bov[nj] = bo[n]; g2v[nj] = g2[n]; b2vv[nj] = b2v[n];
  }
#pragma unroll
  for (int mi=0;mi<2;mi++)
#pragma unroll
  for (int r=0;r<4;r++){
    int p = 32*s + mi*16 + 4*lg + r;       // row in window
    int hh_ = (wh*8 + (p >> 3) + 4) & 63;
    int ww_ = (wwi*8 + (p & 7) + 4) & 63;
    size_t base = ((size_t)bi*4096 + hh_*64 + ww_)*256;
    float ls = 0.f, lq = 0.f;
#pragma unroll
    for (int nj=0;nj<2;nj++){
      int n = 32*h + nj*16 + lr;
      float v = po[mi][nj][r] + bov[nj] + hidden[base + n];
      hs_out[base + n] = v;
      po[mi][nj][r] = v;
      ls += v; lq += v*v;
    }
    ls += __shfl_xor(ls,1); lq += __shfl_xor(lq,1);
    ls += __shfl_xor(ls,2); lq += __shfl_xor(lq,2);
    ls += __shfl_xor(ls,4); lq += __shfl_xor(lq,4);
    ls += __shfl_xor(ls,8); lq += __shfl_xor(lq,8);
    if (lr == 0){ part_s[p*8 + h] = ls; part_q[p*8 + h] = lq; }
  }
  __syncthreads();

  // ---- Phase 9: LN2 finalize -> y2 bf16 (token order) ----
#pragma unroll
  for (int mi=0;mi<2;mi++)
#pragma unroll
  for (int r=0;r<4;r++){
    int p = 32*s + mi*16 + 4*lg + r;
    int hh_ = (wh*8 + (p >> 3) + 4) & 63;
    int ww_ = (wwi*8 + (p & 7) + 4) & 63;
    size_t base = ((size_t)bi*4096 + hh_*64 + ww_)*256;
    float sum = 0.f, sqq = 0.f;
#pragma unroll
    for (int hh2=0; hh2<8; hh2++){ sum += part_s[p*8 + hh2]; sqq += part_q[p*8 + hh2]; }
    float mean = sum*(1.f/256.f);
    float inv = rsqrtf(sqq*(1.f/256.f) - mean*mean + 1e-5f);
#pragma unroll
    for (int nj=0;nj<2;nj++){
      int n = 32*h + nj*16 + lr;
      y2[base + n] = f2bf((po[mi][nj][r]-mean)*inv*g2v[nj] + b2vv[nj]);
    }
  }
}

// ============ 256x256-tile GEMM: A[M][K] (LDS dbuf) @ Wfrag (L2-direct) ============
// 8 waves (2M x 4N), BK=64, A-only staging (64KB LDS -> 2 blocks/CU),
// B fragments prefetched into registers across barriers.
// vmcnt ledger: at top of iter t, ops newer than A(t) = BLOAD(t)[8] +
// GSTAGE_A(t+1)[4 if exists] -> vmcnt(12) / vmcnt(8) on last iter.
#define GSTAGE_A(buf, k0)                                                \
  _Pragma("unroll")                                                      \
  for (int c = 0; c < 4; c++){                                           \
    int row = c*64 + srow;                                               \
    gll16(Aw + (size_t)row*K + (k0) + (scb>>1), &As[buf][c*4096 + tid*8]); \
  }

#define BLOAD(t)                                                         \
  _Pragma("unroll")                                                      \
  for (int kk = 0; kk < 2; kk++){                                        \
    int ks = ((t)<<1) + kk;                                              \
    _Pragma("unroll")                                                    \
    for (int j = 0; j < 4; j++)                                          \
      bfr[kk][j] = *(const bf16x8*)(WF + ((((size_t)(nb16 + wc*4 + j))*nks + ks)<<9) + lane*8); \
  }

#define GLOOP_BODY(b)                                                    \
  _Pragma("unroll")                                                      \
  for (int kk = 0; kk < 2; kk++){                                        \
    int cbr = (kk*64 + 16*g) ^ ((lr & 7) << 4);                          \
    bf16x8 af[8];                                                        \
    _Pragma("unroll")                                                    \
    for (int i=0;i<8;i++)                                                \
      af[i] = *(const bf16x8*)(&As[b][(wr*128 + i*16 + lr)*64 + (cbr>>1)]); \
    _Pragma("unroll")                                                    \
    for (int mi=0;mi<8;mi++)                                             \
    _Pragma("unroll")                                                    \
    for (int nj=0;nj<4;nj++)                                             \
      acc[mi][nj] = MFMA_BF16(af[mi], bfr[kk][nj], acc[mi][nj], 0,0,0);  \
  }

#define GLOOP(nt)                                                        \
  GSTAGE_A(0, 0)                                                         \
  GSTAGE_A(1, 64)                                                        \
  BLOAD(0)                                                               \
  for (int t = 0; t < (nt); t++){                                        \
    if (t+1 < (nt)) asm volatile("s_waitcnt vmcnt(12)" ::: "memory");    \
    else            asm volatile("s_waitcnt vmcnt(8)" ::: "memory");     \
    __builtin_amdgcn_s_barrier();                                        \
    __builtin_amdgcn_sched_barrier(0);                                   \
    int b = t & 1;                                                       \
    GLOOP_BODY(b)                                                        \
    __builtin_amdgcn_sched_barrier(0);                                   \
    asm volatile("s_waitcnt lgkmcnt(0)" ::: "memory");                   \
    __builtin_amdgcn_s_barrier();                                        \
    __builtin_amdgcn_sched_barrier(0);                                   \
    if (t+1 < (nt)){ BLOAD(t+1) }                                        \
    if (t+2 < (nt)){ GSTAGE_A(b, (t+2)<<6) }                             \
  }

// EPI 2: +b1, exact GELU, bf16 row-major out [m][1024]
// EPI 3: +b2, +hs residual (fp32), fp32 out
template<int EPI, bool SWZ>
__global__ __launch_bounds__(512, 2) void k_gemm256(const u16* __restrict__ A, const u16* __restrict__ WF,
                                                    const float* __restrict__ bias, const float* __restrict__ res,
                                                    void* __restrict__ outp, int K){
  __shared__ __align__(16) u16 As[2][16384];
  int tid = threadIdx.x, lane = tid & 63, wid = tid >> 6;
  int g = lane >> 4, lr = lane & 15;
  int wr = wid >> 2, wc = wid & 3;
  int bx, by;
  if constexpr (SWZ){
    int nwg = gridDim.x*gridDim.y;
    int bid = blockIdx.y*gridDim.x + blockIdx.x;
    int cpx = nwg >> 3;
    int swz = (bid & 7)*cpx + (bid >> 3);
    bx = swz % gridDim.x; by = swz / gridDim.x;
  } else { bx = blockIdx.x; by = blockIdx.y; }
  int m0 = by*256, n0 = bx*256;
  int nb16 = bx << 4;
  int nks = K >> 5;
  const u16* Aw = A + (size_t)m0*K;
  int srow = tid >> 3;
  int scb  = ((tid & 7)*16) ^ ((srow & 7) << 4);
  f32x4 acc[8][4] = {};
  bf16x8 bfr[2][4];
  int nt = K >> 6;

  GLOOP(nt)

#pragma unroll
  for (int mi=0; mi<8; mi++)
#pragma unroll
  for (int nj=0; nj<4; nj++){
    int n = n0 + wc*64 + nj*16 + lr;
#pragma unroll
    for (int r=0; r<4; r++){
      int m = m0 + wr*128 + mi*16 + 4*g + r;
      float val = acc[mi][nj][r] + bias[n];
      if constexpr (EPI==2){
        float gv = 0.5f*val*(1.f + erff(val*0.70710678118654752f));
        ((u16*)outp)[(size_t)m*1024 + n] = f2bf(gv);
      } else {
        ((float*)outp)[(size_t)m*256 + n] = val + res[(size_t)m*256 + n];
      }
    }
  }
}

extern "C" void kernel_launch(void* const* d_in, const int* in_sizes, int n_in,
                              void* d_out, int out_size, void* d_ws, size_t ws_size,
                              hipStream_t stream){
  const float* hidden = (const float*)d_in[0];
  const float* ln1g = (const float*)d_in[1];
  const float* ln1b = (const float*)d_in[2];
  const float* wq   = (const float*)d_in[3];
  const float* bq   = (const float*)d_in[4];
  const float* wk   = (const float*)d_in[5];
  const float* bk   = (const float*)d_in[6];
  const float* wv   = (const float*)d_in[7];
  const float* bv   = (const float*)d_in[8];
  const float* btab = (const float*)d_in[9];
  const float* wo   = (const float*)d_in[10];
  const float* bo   = (const float*)d_in[11];
  const float* ln2g = (const float*)d_in[12];
  const float* ln2b = (const float*)d_in[13];
  const float* w1   = (const float*)d_in[14];
  const float* b1   = (const float*)d_in[15];
  const float* w2   = (const float*)d_in[16];
  const float* b2   = (const float*)d_in[17];
  float* out = (float*)d_out;

  char* ws = (char*)d_ws;
  const size_t MB = 1ull << 20;
  u16* y1c   = (u16*)(ws + 64*MB);       // [64M,192M): FC1 chunk out
  u16* y2ln  = (u16*)(ws + 192*MB);      // [192M,256M): LN2 out
  u16* fragW = (u16*)(ws + 256*MB);      // QKV weights, fragment-major (384KB)
  u16* woF   = fragW + 196608;           // 16*8*512  = 65536 u16
  u16* w1F   = woF + 65536;              // 64*8*512  = 262144 u16
  u16* w2F   = w1F + 262144;             // 16*32*512 = 262144 u16
  float* bqkv = (float*)(w2F + 262144);
  float* fbias = bqkv + 1024;            // 4*8*64*64 fp32 = 512KB

  // weight prep
  k_fragw<<<768, 256, 0, stream>>>(wq, wk, wv, fragW);
  k_wfrag<<<256, 256, 0, stream>>>(wo, woF, 256, 256);
  k_wfrag<<<1024,256, 0, stream>>>(w1, w1F, 256, 1024);
  k_wfrag<<<1024,256, 0, stream>>>(w2, w2F, 1024, 256);
  k_concat_bias<<<1, 768, 0, stream>>>(bq, bk, bv, bqkv);
  k_bias<<<512, 256, 0, stream>>>(btab, fbias);

  // fused LN1 + shift + QKV + attention + O-proj + residual -> hs (d_out), LN2 -> y2ln
  k_fattn<<<2048, 1024, 0, stream>>>(hidden, ln1g, ln1b, fragW, bqkv, fbias,
                                     woF, bo, ln2g, ln2b, out, y2ln);
  // MLP in 2 M-chunks of 65536 rows
  for (int mc = 0; mc < 2; mc++){
    k_gemm256<2,true><<<dim3(4, 256), 512, 0, stream>>>(y2ln + (size_t)mc*65536*256, w1F, b1, nullptr, y1c, 256);
    k_gemm256<3,false><<<dim3(1, 256), 512, 0, stream>>>(y1c, w2F, b2,
                                                         out + (size_t)mc*65536*256,
                                                         out + (size_t)mc*65536*256, 1024);
  }
}

// Round 13
// 536.626 us; speedup vs baseline: 4.2693x; 1.0423x over previous
//
#include <hip/hip_runtime.h>
#include <hip/hip_bf16.h>
#include <math.h>

typedef unsigned short u16;
typedef __attribute__((ext_vector_type(8))) short bf16x8;
typedef __attribute__((ext_vector_type(8))) unsigned short u16x8;
typedef __attribute__((ext_vector_type(4))) float f32x4;

#define MFMA_BF16 __builtin_amdgcn_mfma_f32_16x16x32_bf16

__device__ __forceinline__ u16 f2bf(float f){
  union { float f; unsigned u; } v; v.f = f;
  unsigned r = v.u + 0x7FFFu + ((v.u >> 16) & 1u);
  return (u16)(r >> 16);
}

__device__ __forceinline__ void gll16(const void* g, void* l){
  __builtin_amdgcn_global_load_lds(
      (const __attribute__((address_space(1))) unsigned int*)g,
      (__attribute__((address_space(3))) unsigned int*)l, 16, 0, 0);
}

__global__ void k_concat_bias(const float* __restrict__ a, const float* __restrict__ b,
                              const float* __restrict__ c, float* __restrict__ o){
  int i = threadIdx.x;  // 768 threads
  o[i] = i < 256 ? a[i] : (i < 512 ? b[i-256] : c[i-512]);
}

// ---- weights -> MFMA-fragment-major: F[n16][ks][lane][8] = W[k][n],
// k = ks*32 + (lane>>4)*8 + j, n = n16*16 + (lane&15)
__global__ __launch_bounds__(256) void k_wfrag(const float* __restrict__ W, u16* __restrict__ F,
                                               int K, int N){
  int idx = blockIdx.x*256 + threadIdx.x;
  int nks = K >> 5;
  int per_n16 = nks << 9;
  int n16 = idx / per_n16; int rem = idx - n16*per_n16;
  int ks = rem >> 9, l8 = rem & 511, lane = l8 >> 3, j = l8 & 7;
  int k = ks*32 + ((lane >> 4) << 3) + j;
  int n = (n16 << 4) + (lane & 15);
  F[idx] = f2bf(W[(size_t)k*N + n]);
}

// ---- QKV weights fragment-major (per head) ----
__global__ __launch_bounds__(256) void k_fragw(const float* __restrict__ wq, const float* __restrict__ wk,
                                               const float* __restrict__ wv, u16* __restrict__ fragW){
  int idx = blockIdx.x*256 + threadIdx.x;    // 3*65536
  int j = idx & 7, lane = (idx >> 3) & 63, nj = (idx >> 9) & 1;
  int ks = (idx >> 10) & 7, h = (idx >> 13) & 7, type = idx >> 16;
  const float* w = type == 0 ? wq : (type == 1 ? wk : wv);
  int k = ks*32 + 8*(lane >> 4) + j;
  int n = h*32 + nj*16 + (lane & 15);
  fragW[idx] = f2bf(w[(size_t)k*256 + n]);
}

// ---- fused rel-pos bias + shift mask, fragment layout: fb2[cls][h][m][lr][nj] ----
__global__ __launch_bounds__(256) void k_bias(const float* __restrict__ btab, float* __restrict__ fb){
  int idx = blockIdx.x*256 + threadIdx.x;   // 4*8*64*64 = 131072
  int nj = idx & 3, lr = (idx >> 2) & 15, m = (idx >> 6) & 63, hh = (idx >> 12) & 7, cls = idx >> 15;
  int n = nj*16 + lr;
  int r1=m>>3, c1=m&7, r2=n>>3, c2=n&7;
  float bv = btab[((r1-r2+7)*15 + (c1-c2+7))*8 + hh];
  int whe = cls>>1, wwe = cls&1;
  int a1 = (whe ? (r1<4?1:2) : 0)*3 + (wwe ? (c1<4?1:2) : 0);
  int a2 = (whe ? (r2<4?1:2) : 0)*3 + (wwe ? (c2<4?1:2) : 0);
  fb[idx] = bv + ((a1!=a2) ? -100.f : 0.f);
}

// ======== FUSED LN1 + QKV + windowed attention + O-proj + residual + LN2 ========
// One block per window (2048). 16 waves = 8 heads x 2 token-halves.
__global__ __launch_bounds__(1024) void k_fattn(const float* __restrict__ hidden,
    const float* __restrict__ g1, const float* __restrict__ b1f,
    const u16* __restrict__ fragW, const float* __restrict__ bqkv,
    const float* __restrict__ fb, const u16* __restrict__ woF,
    const float* __restrict__ bo, const float* __restrict__ g2,
    const float* __restrict__ b2v,
    float* __restrict__ hs_out, u16* __restrict__ y2)
{
  __shared__ __align__(16) u16 lds[75776];   // 151552 B
  int tid = threadIdx.x, lane = tid & 63, wid = tid >> 6;
  int lg = lane >> 4, lr = lane & 15;
  int h = wid >> 1, s = wid & 1;
  int gw = blockIdx.x;
  int bi = gw >> 6, win = gw & 63, wh = win >> 3, wwi = win & 7;

  // ---- Phase 1: LN1 + cyclic-shift gather -> xb (chunk-XOR swizzled) ----
  {
    int t = wid*4 + (lane >> 4);           // token 0..63 (16 lanes/token)
    int j = lane & 15;                     // 16-channel slice
    int hh_ = (wh*8 + (t >> 3) + 4) & 63;
    int ww_ = (wwi*8 + (t & 7) + 4) & 63;
    const float4* row = (const float4*)(hidden + ((size_t)bi*4096 + hh_*64 + ww_)*256) + j*4;
    float4 v[4]; float sm = 0.f, sq = 0.f;
#pragma unroll
    for (int i=0;i<4;i++){
      v[i] = row[i];
      sm += v[i].x+v[i].y+v[i].z+v[i].w;
      sq += v[i].x*v[i].x+v[i].y*v[i].y+v[i].z*v[i].z+v[i].w*v[i].w;
    }
    sm += __shfl_xor(sm,1); sq += __shfl_xor(sq,1);
    sm += __shfl_xor(sm,2); sq += __shfl_xor(sq,2);
    sm += __shfl_xor(sm,4); sq += __shfl_xor(sq,4);
    sm += __shfl_xor(sm,8); sq += __shfl_xor(sq,8);
    float mean = sm*(1.f/256.f);
    float inv = rsqrtf(sq*(1.f/256.f) - mean*mean + 1e-5f);
    const float4* gg = (const float4*)g1 + j*4;
    const float4* bb = (const float4*)b1f + j*4;
#pragma unroll
    for (int i2=0;i2<2;i2++){
      float4 a0=v[2*i2], a1=v[2*i2+1];
      float4 g0=gg[2*i2], g1_=gg[2*i2+1];
      float4 b0=bb[2*i2], b1_=bb[2*i2+1];
      u16x8 pk;
      pk[0]=f2bf((a0.x-mean)*inv*g0.x+b0.x); pk[1]=f2bf((a0.y-mean)*inv*g0.y+b0.y);
      pk[2]=f2bf((a0.z-mean)*inv*g0.z+b0.z); pk[3]=f2bf((a0.w-mean)*inv*g0.w+b0.w);
      pk[4]=f2bf((a1.x-mean)*inv*g1_.x+b1_.x); pk[5]=f2bf((a1.y-mean)*inv*g1_.y+b1_.y);
      pk[6]=f2bf((a1.z-mean)*inv*g1_.z+b1_.z); pk[7]=f2bf((a1.w-mean)*inv*g1_.w+b1_.w);
      int c = (j*2 + i2) ^ (t & 7);
      *(u16x8*)(&lds[t*256 + c*8]) = pk;
    }
  }
  __syncthreads();

  // ---- Phase 2: mini-GEMM q/k/v for head h, token half s (fragW from L2) ----
  f32x4 qa[2][2]={}, ka[2][2]={}, va[2][2]={};
  __builtin_amdgcn_s_setprio(1);
#pragma unroll
  for (int ks=0; ks<8; ks++){
    bf16x8 af[2];
#pragma unroll
    for (int mi=0;mi<2;mi++){
      int tok = 32*s + mi*16 + lr;
      af[mi] = *(const bf16x8*)(&lds[tok*256 + (((ks*4+lg) ^ (tok&7))*8)]);
    }
    const u16* fq = fragW + ((((size_t)h)*8 + ks)*2)*512 + lane*8;
#pragma unroll
    for (int nj=0;nj<2;nj++){
      bf16x8 bq_ = *(const bf16x8*)(fq + nj*512);
      bf16x8 bk_ = *(const bf16x8*)(fq + 65536 + nj*512);
      bf16x8 bv_ = *(const bf16x8*)(fq + 131072 + nj*512);
#pragma unroll
      for (int mi=0;mi<2;mi++){
        qa[mi][nj] = MFMA_BF16(af[mi], bq_, qa[mi][nj], 0,0,0);
        ka[mi][nj] = MFMA_BF16(af[mi], bk_, ka[mi][nj], 0,0,0);
        va[mi][nj] = MFMA_BF16(af[mi], bv_, va[mi][nj], 0,0,0);
      }
    }
  }
  __builtin_amdgcn_s_setprio(0);

  // ---- Phase 3: q/k/v -> per-head arena (each wave writes its token half) ----
  u16* hb  = &lds[16384 + h*7424];
  u16* k_h = hb;                    // [64][40]
  u16* v_h = hb + 2560;             // [32 dims][72]
  u16* q_s = hb + 4864 + s*1280;    // [32][40]
  const float scale = 0.1767766952966369f; // 32^-0.5
#pragma unroll
  for (int mi=0;mi<2;mi++)
#pragma unroll
  for (int nj=0;nj<2;nj++){
    int dim = nj*16+lr;
    float bq_ = bqkv[h*32+dim], bk_ = bqkv[256+h*32+dim], bv_ = bqkv[512+h*32+dim];
#pragma unroll
    for (int r=0;r<4;r++){
      int tokl = mi*16+4*lg+r;            // local 0..31
      q_s[tokl*40+dim] = f2bf((qa[mi][nj][r]+bq_)*scale);
      k_h[(32*s+tokl)*40+dim] = f2bf(ka[mi][nj][r]+bk_);
    }
    ushort4 vp;
    vp.x = f2bf(va[mi][nj][0]+bv_); vp.y = f2bf(va[mi][nj][1]+bv_);
    vp.z = f2bf(va[mi][nj][2]+bv_); vp.w = f2bf(va[mi][nj][3]+bv_);
    *(ushort4*)(&v_h[dim*72 + 32*s + mi*16 + 4*lg]) = vp;
  }
  __syncthreads();   // k_h/v_h halves from both waves visible

  // ---- Phase 4: QK^T (32 q-rows x 64 k) + bias/mask + softmax ----
  bf16x8 qf[2], kf[4];
#pragma unroll
  for (int i=0;i<2;i++)
    qf[i] = *(const bf16x8*)(&q_s[(i*16+lr)*40 + 8*lg]);
#pragma unroll
  for (int i=0;i<4;i++)
    kf[i] = *(const bf16x8*)(&k_h[(i*16+lr)*40 + 8*lg]);
  f32x4 acc[2][4] = {};
#pragma unroll
  for (int mi=0;mi<2;mi++)
#pragma unroll
  for (int nj=0;nj<4;nj++)
    acc[mi][nj] = MFMA_BF16(qf[mi], kf[nj], acc[mi][nj], 0,0,0);

  int cls = ((wh==7) ? 2 : 0) | ((wwi==7) ? 1 : 0);
  const float4* fb4 = (const float4*)(fb + (((size_t)cls*8 + h) << 12));
#pragma unroll
  for (int mi=0;mi<2;mi++)
#pragma unroll
  for (int r=0;r<4;r++){
    int m = 32*s + mi*16 + 4*lg + r;
    float4 bv4 = fb4[m*16 + lr];
#pragma unroll
    for (int nj=0;nj<4;nj++)
      acc[mi][nj][r] += bv4[nj];
  }
#pragma unroll
  for (int mi=0;mi<2;mi++)
#pragma unroll
  for (int r=0;r<4;r++){
    float mx = fmaxf(fmaxf(acc[mi][0][r], acc[mi][1][r]), fmaxf(acc[mi][2][r], acc[mi][3][r]));
    for (int off=1; off<16; off<<=1) mx = fmaxf(mx, __shfl_xor(mx, off));
    float sum = 0.f;
#pragma unroll
    for (int nj=0;nj<4;nj++){ float e = __expf(acc[mi][nj][r]-mx); acc[mi][nj][r]=e; sum+=e; }
    for (int off=1; off<16; off<<=1) sum += __shfl_xor(sum, off);
    float inv = 1.f/sum;
#pragma unroll
    for (int nj=0;nj<4;nj++) acc[mi][nj][r] *= inv;
  }

  // P overwrites k/q regions read by partner's QK^T; also all phase-2 xb reads
  // must be done before the out-tile overwrites xb below -> block sync.
  __syncthreads();

  u16* P_s = s ? hb : (hb + 4864);   // [32][72], wave-private
#pragma unroll
  for (int mi=0;mi<2;mi++)
#pragma unroll
  for (int nj=0;nj<4;nj++)
#pragma unroll
  for (int r=0;r<4;r++)
    P_s[(mi*16+4*lg+r)*72 + nj*16 + lr] = f2bf(acc[mi][nj][r]);

  // ---- Phase 5: PV (own 32 rows x full V) ----
  f32x4 acc2[2][2] = {};
#pragma unroll
  for (int ks=0; ks<2; ks++){
    bf16x8 vf0 = *(const bf16x8*)(&v_h[(lr)*72 + ks*32 + 8*lg]);
    bf16x8 vf1 = *(const bf16x8*)(&v_h[(16+lr)*72 + ks*32 + 8*lg]);
#pragma unroll
    for (int mi=0;mi<2;mi++){
      bf16x8 pf = *(const bf16x8*)(&P_s[(mi*16+lr)*72 + ks*32 + 8*lg]);
      acc2[mi][0] = MFMA_BF16(pf, vf0, acc2[mi][0], 0,0,0);
      acc2[mi][1] = MFMA_BF16(pf, vf1, acc2[mi][1], 0,0,0);
    }
  }

  // ---- Phase 6: attn-out tile -> xb (same chunk-XOR swizzle) ----
#pragma unroll
  for (int mi=0;mi<2;mi++)
#pragma unroll
  for (int nt=0;nt<2;nt++)
#pragma unroll
  for (int r=0;r<4;r++){
    int row = 32*s + mi*16 + 4*lg + r;
    int chunk = (4*h + 2*nt + (lr>>3)) ^ (row & 7);
    lds[row*256 + chunk*8 + (lr&7)] = f2bf(acc2[mi][nt][r]);
  }
  __syncthreads();   // full 64x256 out tile visible; arenas now dead

  // ---- Phase 7: O-proj mini-GEMM: rows 32s..+31, cols 32h..+31, K=256 ----
  f32x4 po[2][2] = {};
  __builtin_amdgcn_s_setprio(1);
#pragma unroll
  for (int ks=0; ks<8; ks++){
    bf16x8 af2[2];
#pragma unroll
    for (int mi=0;mi<2;mi++){
      int row = 32*s + mi*16 + lr;
      af2[mi] = *(const bf16x8*)(&lds[row*256 + (((ks*4+lg) ^ (row&7))*8)]);
    }
#pragma unroll
    for (int nj=0;nj<2;nj++){
      bf16x8 bw = *(const bf16x8*)(woF + (((size_t)(2*h+nj))*8 + ks)*512 + lane*8);
#pragma unroll
      for (int mi=0;mi<2;mi++)
        po[mi][nj] = MFMA_BF16(af2[mi], bw, po[mi][nj], 0,0,0);
    }
  }
  __builtin_amdgcn_s_setprio(0);

  // ---- Phase 8: +bo, window-reverse residual, hs -> d_out, LN2 partials ----
  float* part_s = (float*)&lds[16384];          // [64][8]
  float* part_q = (float*)&lds[16384 + 1024];   // [64][8]
  float bov[2], g2v[2], b2vv[2];
#pragma unroll
  for (int nj=0;nj<2;nj++){
    int n = 32*h + nj*16 + lr;
    bov[nj] = bo[n]; g2v[nj] = g2[n]; b2vv[nj] = b2v[n];
  }
#pragma unroll
  for (int mi=0;mi<2;mi++)
#pragma unroll
  for (int r=0;r<4;r++){
    int p = 32*s + mi*16 + 4*lg + r;       // row in window
    int hh_ = (wh*8 + (p >> 3) + 4) & 63;
    int ww_ = (wwi*8 + (p & 7) + 4) & 63;
    size_t base = ((size_t)bi*4096 + hh_*64 + ww_)*256;
    float ls = 0.f, lq = 0.f;
#pragma unroll
    for (int nj=0;nj<2;nj++){
      int n = 32*h + nj*16 + lr;
      float v = po[mi][nj][r] + bov[nj] + hidden[base + n];
      hs_out[base + n] = v;
      po[mi][nj][r] = v;
      ls += v; lq += v*v;
    }
    ls += __shfl_xor(ls,1); lq += __shfl_xor(lq,1);
    ls += __shfl_xor(ls,2); lq += __shfl_xor(lq,2);
    ls += __shfl_xor(ls,4); lq += __shfl_xor(lq,4);
    ls += __shfl_xor(ls,8); lq += __shfl_xor(lq,8);
    if (lr == 0){ part_s[p*8 + h] = ls; part_q[p*8 + h] = lq; }
  }
  __syncthreads();

  // ---- Phase 9: LN2 finalize -> y2 bf16 (token order) ----
#pragma unroll
  for (int mi=0;mi<2;mi++)
#pragma unroll
  for (int r=0;r<4;r++){
    int p = 32*s + mi*16 + 4*lg + r;
    int hh_ = (wh*8 + (p >> 3) + 4) & 63;
    int ww_ = (wwi*8 + (p & 7) + 4) & 63;
    size_t base = ((size_t)bi*4096 + hh_*64 + ww_)*256;
    float sum = 0.f, sqq = 0.f;
#pragma unroll
    for (int hh2=0; hh2<8; hh2++){ sum += part_s[p*8 + hh2]; sqq += part_q[p*8 + hh2]; }
    float mean = sum*(1.f/256.f);
    float inv = rsqrtf(sqq*(1.f/256.f) - mean*mean + 1e-5f);
#pragma unroll
    for (int nj=0;nj<2;nj++){
      int n = 32*h + nj*16 + lr;
      y2[base + n] = f2bf((po[mi][nj][r]-mean)*inv*g2v[nj] + b2vv[nj]);
    }
  }
}

// ======== FUSED MLP: out = hs + GELU(y2 @ w1 + b1) @ w2 + b2, K-split over d_ff ========
// One block per 64 rows (2048 blocks). 8 waves, 64KB LDS (2 blocks/CU).
// y1 NEVER touches HBM: per c-slice (256 of 1024 ff-cols),
//   FC1: wave w computes t[64][w*32..+32] -> GELU -> swizzled LDS tile
//   FC2: wave (wr,wc) accumulates y2[32wr..+32][64wc..+64] over the c-slice.
__global__ __launch_bounds__(512) void k_mlp(const u16* __restrict__ y2ln,
    const u16* __restrict__ w1F, const u16* __restrict__ w2F,
    const float* __restrict__ b1, const float* __restrict__ b2,
    float* __restrict__ io)
{
  __shared__ __align__(16) u16 lds[32768];   // xb [0,16384) + t [16384,32768)
  int tid = threadIdx.x, lane = tid & 63, wid = tid >> 6;
  int lg = lane >> 4, lr = lane & 15;
  int wr_ = wid >> 2, wc_ = wid & 3;
  int m0 = blockIdx.x*64;

  // stage x = y2ln rows m0..+64 into xb, chunk-XOR swizzled via pre-swizzled source
  {
    int row_lo = tid >> 5;           // 0..15
    int ch = tid & 31;               // 16B chunk within 512B row
#pragma unroll
    for (int i=0;i<4;i++){
      int row = i*16 + row_lo;
      int sch = ch ^ (row & 7);
      gll16(y2ln + (size_t)(m0+row)*256 + sch*8, &lds[i*4096 + tid*8]);
    }
  }
  asm volatile("s_waitcnt vmcnt(0)" ::: "memory");
  __syncthreads();

  u16* xt = &lds[16384];
  f32x4 accY[2][4] = {};
  float b2v[4];
#pragma unroll
  for (int nj=0;nj<4;nj++) b2v[nj] = b2[wc_*64 + nj*16 + lr];

  for (int c = 0; c < 4; c++){
    // ---- FC1: t_c[64][wid*32..+32] = x @ w1[:, c*256 + wid*32 ..], K=256 ----
    f32x4 acc1[4][2] = {};
    __builtin_amdgcn_s_setprio(1);
#pragma unroll
    for (int ks=0; ks<8; ks++){
      bf16x8 af[4];
#pragma unroll
      for (int mi=0;mi<4;mi++){
        int row = mi*16 + lr;
        af[mi] = *(const bf16x8*)(&lds[row*256 + (((ks*4+lg) ^ (row&7))<<3)]);
      }
#pragma unroll
      for (int nj=0;nj<2;nj++){
        bf16x8 bw = *(const bf16x8*)(w1F + ((((size_t)(c*16 + wid*2 + nj))*8 + ks)<<9) + lane*8);
#pragma unroll
        for (int mi=0;mi<4;mi++)
          acc1[mi][nj] = MFMA_BF16(af[mi], bw, acc1[mi][nj], 0,0,0);
      }
    }
    __builtin_amdgcn_s_setprio(0);
    __syncthreads();   // previous FC2's t-reads complete before overwrite
    // GELU + write t (swizzled)
#pragma unroll
    for (int mi=0;mi<4;mi++)
#pragma unroll
    for (int nj=0;nj<2;nj++){
      float b1v = b1[c*256 + wid*32 + nj*16 + lr];
#pragma unroll
      for (int r=0;r<4;r++){
        int row = mi*16 + 4*lg + r;
        int col = wid*32 + nj*16 + lr;
        float v = acc1[mi][nj][r] + b1v;
        v = 0.5f*v*(1.f + erff(v*0.70710678118654752f));
        xt[row*256 + ((((col>>3) ^ (row&7))<<3) | (col&7))] = f2bf(v);
      }
    }
    __syncthreads();   // t_c fully visible
    // ---- FC2: accY += t_c[32wr_..+32][:] @ w2[c*256..+256][64wc_..+64] ----
    __builtin_amdgcn_s_setprio(1);
#pragma unroll
    for (int ks=0; ks<8; ks++){
      bf16x8 af2[2];
#pragma unroll
      for (int mi=0;mi<2;mi++){
        int row = wr_*32 + mi*16 + lr;
        af2[mi] = *(const bf16x8*)(&xt[row*256 + (((ks*4+lg) ^ (row&7))<<3)]);
      }
#pragma unroll
      for (int nj=0;nj<4;nj++){
        bf16x8 bw = *(const bf16x8*)(w2F + ((((size_t)(wc_*4 + nj))*32 + c*8 + ks)<<9) + lane*8);
#pragma unroll
        for (int mi=0;mi<2;mi++)
          accY[mi][nj] = MFMA_BF16(af2[mi], bw, accY[mi][nj], 0,0,0);
      }
    }
    __builtin_amdgcn_s_setprio(0);
  }

  // ---- epilogue: out = accY + b2 + hs (in place, fp32) ----
#pragma unroll
  for (int mi=0;mi<2;mi++)
#pragma unroll
  for (int nj=0;nj<4;nj++)
#pragma unroll
  for (int r=0;r<4;r++){
    int m = m0 + wr_*32 + mi*16 + 4*lg + r;
    int n = wc_*64 + nj*16 + lr;
    io[(size_t)m*256 + n] = accY[mi][nj][r] + b2v[nj] + io[(size_t)m*256 + n];
  }
}

extern "C" void kernel_launch(void* const* d_in, const int* in_sizes, int n_in,
                              void* d_out, int out_size, void* d_ws, size_t ws_size,
                              hipStream_t stream){
  const float* hidden = (const float*)d_in[0];
  const float* ln1g = (const float*)d_in[1];
  const float* ln1b = (const float*)d_in[2];
  const float* wq   = (const float*)d_in[3];
  const float* bq   = (const float*)d_in[4];
  const float* wk   = (const float*)d_in[5];
  const float* bk   = (const float*)d_in[6];
  const float* wv   = (const float*)d_in[7];
  const float* bv   = (const float*)d_in[8];
  const float* btab = (const float*)d_in[9];
  const float* wo   = (const float*)d_in[10];
  const float* bo   = (const float*)d_in[11];
  const float* ln2g = (const float*)d_in[12];
  const float* ln2b = (const float*)d_in[13];
  const float* w1   = (const float*)d_in[14];
  const float* b1   = (const float*)d_in[15];
  const float* w2   = (const float*)d_in[16];
  const float* b2   = (const float*)d_in[17];
  float* out = (float*)d_out;

  char* ws = (char*)d_ws;
  const size_t MB = 1ull << 20;
  u16* y2ln  = (u16*)(ws + 192*MB);      // LN2 out (64MB)
  u16* fragW = (u16*)(ws + 256*MB);      // QKV weights, fragment-major (384KB)
  u16* woF   = fragW + 196608;           // 16*8*512  = 65536 u16
  u16* w1F   = woF + 65536;              // 64*8*512  = 262144 u16
  u16* w2F   = w1F + 262144;             // 16*32*512 = 262144 u16
  float* bqkv = (float*)(w2F + 262144);
  float* fbias = bqkv + 1024;            // 4*8*64*64 fp32 = 512KB

  // weight prep
  k_fragw<<<768, 256, 0, stream>>>(wq, wk, wv, fragW);
  k_wfrag<<<256, 256, 0, stream>>>(wo, woF, 256, 256);
  k_wfrag<<<1024,256, 0, stream>>>(w1, w1F, 256, 1024);
  k_wfrag<<<1024,256, 0, stream>>>(w2, w2F, 1024, 256);
  k_concat_bias<<<1, 768, 0, stream>>>(bq, bk, bv, bqkv);
  k_bias<<<512, 256, 0, stream>>>(btab, fbias);

  // fused LN1 + shift + QKV + attention + O-proj + residual -> hs (d_out), LN2 -> y2ln
  k_fattn<<<2048, 1024, 0, stream>>>(hidden, ln1g, ln1b, fragW, bqkv, fbias,
                                     woF, bo, ln2g, ln2b, out, y2ln);
  // fused MLP (FC1 + GELU + FC2 + residual), y1 stays in LDS
  k_mlp<<<2048, 512, 0, stream>>>(y2ln, w1F, w2F, b1, b2, out);
}